// Round 11
// baseline (328.343 us; speedup 1.0000x reference)
//
#include <hip/hip_runtime.h>
#include <hip/hip_fp16.h>

typedef __attribute__((ext_vector_type(8))) short bh8;
typedef __attribute__((ext_vector_type(4))) float fv4;

#define NB 8
#define EB 128
#define BLK 512

#define MFMA(a, b, c) __builtin_amdgcn_mfma_f32_16x16x32_bf16((a), (b), (c), 0, 0, 0)

__device__ __forceinline__ unsigned short f2bf(float x) {
    unsigned int u = __float_as_uint(x);
    u += 0x7fffu + ((u >> 16) & 1u);
    return (unsigned short)(u >> 16);
}
__device__ __forceinline__ float bf2f(unsigned short h) {
    return __uint_as_float(((unsigned int)h) << 16);
}
// element index into a row-major [*][128] bf16 LDS tile, 8-elem XOR swizzle
__device__ __forceinline__ int swz(int row, int col) {
    return row * 128 + ((((col >> 3) ^ (row & 7)) << 3) | (col & 7));
}

// ws layout (ushort): [0,8192) w1T[128][64]; [8192,24576) w2T[128][128];
// [24576,106496) wcT[5][128][128]; [106496, +N*1152) vhf (fp16 value)
__global__ void prep_kernel(
    const float* __restrict__ rad_w1, const float* __restrict__ rad_w2,
    const float* __restrict__ tp_w_same, const float* __restrict__ tp_w_rv0,
    const float* __restrict__ tp_w_rdot, const float* __restrict__ proj_w,
    unsigned short* __restrict__ ws)
{
    unsigned short* w1T = ws;
    unsigned short* w2T = ws + 8192;
    unsigned short* wcT = ws + 24576;
    const int b = blockIdx.x, t = threadIdx.x;
    if (b < 640) {
        const int m = b >> 7, d = b & 127;
        const float* A; const float* B;
        if (m == 0)      { A = tp_w_same;         B = proj_w; }
        else if (m == 1) { A = tp_w_rdot;         B = proj_w; }
        else if (m == 2) { A = tp_w_same + 16384; B = proj_w + 16384; }
        else if (m == 3) { A = tp_w_rv0;          B = proj_w + 16384; }
        else             { A = tp_w_same + 32768; B = proj_w + 32768; }
        __shared__ float Bs[128];
        Bs[t] = B[t * 128 + d];
        __syncthreads();
        float acc = 0.f;
        const float* Ar = A + t * 128;
        #pragma unroll 4
        for (int x = 0; x < 128; ++x) acc = fmaf(Ar[x], Bs[x], acc);
        wcT[m * 16384 + d * 128 + t] = f2bf(acc);
    } else {
        const int bb = b - 640;
        #pragma unroll
        for (int i = 0; i < 12; ++i) {
            const int idx = bb * 1536 + i * 128 + t;
            if (idx < 8192) {
                const int j = idx >> 6, c = idx & 63;
                w1T[idx] = f2bf(rad_w1[c * 128 + j]);
            } else if (idx < 24576) {
                const int i2 = idx - 8192;
                const int j = i2 >> 7, c = i2 & 127;
                w2T[i2] = f2bf(rad_w2[c * 128 + j]);
            }
        }
    }
}

__global__ __launch_bounds__(256) void conv_value_kernel(
    const float* __restrict__ v, unsigned short* __restrict__ o, int n8)
{
    const int i = blockIdx.x * 256 + threadIdx.x;
    if (i >= n8) return;
    const float4 a = *(const float4*)(v + (size_t)i * 8);
    const float4 b = *(const float4*)(v + (size_t)i * 8 + 4);
    uint4 r;
    r.x = (unsigned int)__half_as_ushort(__float2half_rn(a.x)) |
          ((unsigned int)__half_as_ushort(__float2half_rn(a.y)) << 16);
    r.y = (unsigned int)__half_as_ushort(__float2half_rn(a.z)) |
          ((unsigned int)__half_as_ushort(__float2half_rn(a.w)) << 16);
    r.z = (unsigned int)__half_as_ushort(__float2half_rn(b.x)) |
          ((unsigned int)__half_as_ushort(__float2half_rn(b.y)) << 16);
    r.w = (unsigned int)__half_as_ushort(__float2half_rn(b.z)) |
          ((unsigned int)__half_as_ushort(__float2half_rn(b.w)) << 16);
    *(uint4*)(o + (size_t)i * 8) = r;
}

// tpin layout inside the 128-row a-buffer (each tile 16 rows, slot s=ng):
//  T0(r0):  aV0 e | aV1 e | aV2 e | aV3 e      (e = even nodes 2s)
//  T1(r16): aV0 o | aV1 o | aV2 o | aV3 o      (o = odd nodes 2s+1)
//  T2(r32): ard e | ar0 e | ar1 e | ar2 e
//  T3(r48): ard o | ar0 o | ar1 o | ar2 o
//  T4(r64): aV4 e | aV5 e | aV6 e | aV7 e
//  T5(r80): aV4 o | aV5 o | aV6 o | aV7 o
//  T6(r96): aV8 e (0-3) | aV8 o (4-7) | stale (8-15, ignored)
template <int VHALF>
__global__ __launch_bounds__(BLK, 8) void foa_main(
    const float* __restrict__ alpha,        // [N*K*8]
    const float* __restrict__ value,        // [N][9][128] fp32 (fallback)
    const float* __restrict__ x_edge,       // [N*K][64]
    const float* __restrict__ node_pos,     // [N][3]
    const float* __restrict__ edge_dis,     // [N*K]
    const float* __restrict__ exp_node_pos, // [M][3]
    const float* __restrict__ rad_b1, const float* __restrict__ ln_g,
    const float* __restrict__ ln_b, const float* __restrict__ rad_b2,
    const float* __restrict__ proj_b,
    const unsigned short* __restrict__ ws,
    const unsigned short* __restrict__ vhf, // fp16 value table
    const int* __restrict__ outcell_index,
    const int* __restrict__ f_sparse_idx,
    float* __restrict__ out)                // [N][9][128]
{
    // ONE 32 KB buffer: hbuf (ph2) -> a in-place (ph3) -> tpin (parity-split)
    __shared__ __align__(16) unsigned short s_buf[16384];   // 128 rows x 128
    __shared__ float s_alpha[1024];
    __shared__ float s_rE[EB][3];
    __shared__ float s_invd[EB];
    __shared__ int   s_gidx[EB];

    const unsigned short* w1T = ws;
    const unsigned short* w2T = ws + 8192;
    const unsigned short* wcT = ws + 24576;

    const int t = threadIdx.x;
    const int e0 = blockIdx.x * EB;
    const int n0 = blockIdx.x * NB;
    const int lane = t & 63, w = t >> 6;
    const int ln15 = lane & 15, lq = lane >> 4;

    // ---------- phase 0: per-edge metadata ----------
    if (t < EB) {
        const int eidx = f_sparse_idx[e0 + t];
        s_gidx[t] = outcell_index[eidx];
        const int nn = n0 + (t >> 4);
        s_rE[t][0] = node_pos[nn * 3 + 0] - exp_node_pos[(size_t)eidx * 3 + 0];
        s_rE[t][1] = node_pos[nn * 3 + 1] - exp_node_pos[(size_t)eidx * 3 + 1];
        s_rE[t][2] = node_pos[nn * 3 + 2] - exp_node_pos[(size_t)eidx * 3 + 2];
        s_invd[t] = 1.0f / (edge_dis[e0 + t] + 1e-8f);
    }
    s_alpha[t]       = alpha[(size_t)e0 * 8 + t];
    s_alpha[t + 512] = alpha[(size_t)e0 * 8 + 512 + t];
    __syncthreads();

    // ---------- phase 2: GEMM1 ct-blocked + 2-pass LN + SiLU (bf16) -------
    // wave w touches ONLY rows [16w,16w+16) in phases 2-3 -> no barrier
    {
        bh8 af0, af1;
        {
            const float* xp = x_edge + ((size_t)(e0 + 16 * w + ln15)) * 64 + lq * 8;
            const float4 u0 = *(const float4*)(xp);
            const float4 u1 = *(const float4*)(xp + 4);
            const float4 u2 = *(const float4*)(xp + 32);
            const float4 u3 = *(const float4*)(xp + 36);
            af0[0] = (short)f2bf(u0.x); af0[1] = (short)f2bf(u0.y);
            af0[2] = (short)f2bf(u0.z); af0[3] = (short)f2bf(u0.w);
            af0[4] = (short)f2bf(u1.x); af0[5] = (short)f2bf(u1.y);
            af0[6] = (short)f2bf(u1.z); af0[7] = (short)f2bf(u1.w);
            af1[0] = (short)f2bf(u2.x); af1[1] = (short)f2bf(u2.y);
            af1[2] = (short)f2bf(u2.z); af1[3] = (short)f2bf(u2.w);
            af1[4] = (short)f2bf(u3.x); af1[5] = (short)f2bf(u3.y);
            af1[6] = (short)f2bf(u3.z); af1[7] = (short)f2bf(u3.w);
        }
        float sum_[4] = {0.f, 0.f, 0.f, 0.f};
        float sq_[4]  = {0.f, 0.f, 0.f, 0.f};
        #pragma unroll
        for (int ct2 = 0; ct2 < 4; ++ct2) {
            const int ct0 = 2 * ct2, ct1 = ct0 + 1;
            fv4 acc0 = {0.f, 0.f, 0.f, 0.f};
            fv4 acc1 = {0.f, 0.f, 0.f, 0.f};
            const bh8* bp0 = (const bh8*)&w1T[(16 * ct0 + ln15) * 64 + lq * 8];
            const bh8* bp1 = (const bh8*)&w1T[(16 * ct1 + ln15) * 64 + lq * 8];
            acc0 = MFMA(af0, bp0[0], acc0); acc0 = MFMA(af1, bp0[4], acc0);
            acc1 = MFMA(af0, bp1[0], acc1); acc1 = MFMA(af1, bp1[4], acc1);
            const float b0 = rad_b1[16 * ct0 + ln15];
            const float b1 = rad_b1[16 * ct1 + ln15];
            #pragma unroll
            for (int r = 0; r < 4; ++r) {
                const float x0 = acc0[r] + b0;
                const float x1 = acc1[r] + b1;
                sum_[r] += x0 + x1;
                sq_[r]  += x0 * x0 + x1 * x1;
                const int rowg = 16 * w + lq * 4 + r;
                s_buf[swz(rowg, 16 * ct0 + ln15)] = f2bf(x0);
                s_buf[swz(rowg, 16 * ct1 + ln15)] = f2bf(x1);
            }
        }
        float mu_[4], rs_[4];
        #pragma unroll
        for (int r = 0; r < 4; ++r) {
            float s = sum_[r], s2 = sq_[r];
            s += __shfl_xor(s, 1);  s2 += __shfl_xor(s2, 1);
            s += __shfl_xor(s, 2);  s2 += __shfl_xor(s2, 2);
            s += __shfl_xor(s, 4);  s2 += __shfl_xor(s2, 4);
            s += __shfl_xor(s, 8);  s2 += __shfl_xor(s2, 8);
            const float mu = s * 0.0078125f;
            const float var = s2 * 0.0078125f - mu * mu;
            mu_[r] = mu;
            rs_[r] = rsqrtf(var + 1e-5f);
        }
        #pragma unroll
        for (int ct = 0; ct < 8; ++ct) {
            const float g = ln_g[16 * ct + ln15];
            const float b = ln_b[16 * ct + ln15];
            #pragma unroll
            for (int r = 0; r < 4; ++r) {
                const int idx = swz(16 * w + lq * 4 + r, 16 * ct + ln15);
                const float x = bf2f(s_buf[idx]);
                float h = (x - mu_[r]) * rs_[r] * g + b;
                h = h / (1.f + __expf(-h));
                s_buf[idx] = f2bf(h);
            }
        }
    }
    // NO barrier: phase 3 reads/writes only this wave's rows

    // ---------- phase 3: GEMM2 ct-blocked, in-place -> a (bf16) -----------
    {
        bh8 afr[4];
        const int arow = 16 * w + ln15;
        #pragma unroll
        for (int ks = 0; ks < 4; ++ks) {
            const int acb = (lq + 4 * ks) ^ (arow & 7);
            afr[ks] = *(const bh8*)&s_buf[arow * 128 + (acb << 3)];
        }
        #pragma unroll
        for (int ct2 = 0; ct2 < 4; ++ct2) {
            const int ct0 = 2 * ct2, ct1 = ct0 + 1;
            fv4 acc0 = {0.f, 0.f, 0.f, 0.f};
            fv4 acc1 = {0.f, 0.f, 0.f, 0.f};
            #pragma unroll
            for (int ks = 0; ks < 4; ++ks) {
                const bh8 b0 = *(const bh8*)&w2T[(16 * ct0 + ln15) * 128 + lq * 8 + 32 * ks];
                const bh8 b1 = *(const bh8*)&w2T[(16 * ct1 + ln15) * 128 + lq * 8 + 32 * ks];
                acc0 = MFMA(afr[ks], b0, acc0);
                acc1 = MFMA(afr[ks], b1, acc1);
            }
            const float b2_0 = rad_b2[16 * ct0 + ln15];
            const float b2_1 = rad_b2[16 * ct1 + ln15];
            #pragma unroll
            for (int r = 0; r < 4; ++r) {
                const int e = 16 * w + lq * 4 + r;
                const float id = s_invd[e];
                const float a0 = s_alpha[e * 8 + ct0] * (acc0[r] + b2_0) * id;
                const float a1 = s_alpha[e * 8 + ct1] * (acc1[r] + b2_1) * id;
                s_buf[swz(e, 16 * ct0 + ln15)] = f2bf(a0);
                s_buf[swz(e, 16 * ct1 + ln15)] = f2bf(a1);
            }
        }
    }
    __syncthreads();

    // ---------- phase 4: parity-split gather (13 accumulators max) --------
    const int c = t & 127;
    const int ng = t >> 7;
    float aV[9], arr[3], ard;

    #pragma unroll
    for (int ep = 0; ep < 2; ++ep) {
        #pragma unroll
        for (int l = 0; l < 9; ++l) aV[l] = 0.f;
        arr[0] = 0.f; arr[1] = 0.f; arr[2] = 0.f; ard = 0.f;
        #pragma unroll 4
        for (int k = 0; k < 16; ++k) {
            const int e = 32 * ng + 16 * ep + k;
            const float av = bf2f(s_buf[swz(e, c)]);
            float v0, v1, v2, v3, v4, v5, v6, v7, v8;
            if constexpr (VHALF) {
                const __half* vp = (const __half*)vhf + (size_t)s_gidx[e] * 1152 + c;
                v0 = __half2float(vp[0]);    v1 = __half2float(vp[128]);
                v2 = __half2float(vp[256]);  v3 = __half2float(vp[384]);
                v4 = __half2float(vp[512]);  v5 = __half2float(vp[640]);
                v6 = __half2float(vp[768]);  v7 = __half2float(vp[896]);
                v8 = __half2float(vp[1024]);
            } else {
                const float* vp = value + (size_t)s_gidx[e] * 1152 + c;
                v0 = vp[0];    v1 = vp[128];  v2 = vp[256];
                v3 = vp[384];  v4 = vp[512];  v5 = vp[640];
                v6 = vp[768];  v7 = vp[896];  v8 = vp[1024];
            }
            aV[0] = fmaf(av, v0, aV[0]); aV[1] = fmaf(av, v1, aV[1]);
            aV[2] = fmaf(av, v2, aV[2]); aV[3] = fmaf(av, v3, aV[3]);
            aV[4] = fmaf(av, v4, aV[4]); aV[5] = fmaf(av, v5, aV[5]);
            aV[6] = fmaf(av, v6, aV[6]); aV[7] = fmaf(av, v7, aV[7]);
            aV[8] = fmaf(av, v8, aV[8]);
            const float r0 = s_rE[e][0], r1 = s_rE[e][1], r2 = s_rE[e][2];
            const float w0 = av * v0;
            arr[0] = fmaf(r0, w0, arr[0]);
            arr[1] = fmaf(r1, w0, arr[1]);
            arr[2] = fmaf(r2, w0, arr[2]);
            ard = fmaf(av, fmaf(r0, v1, fmaf(r1, v2, r2 * v3)), ard);
        }
        __syncthreads();   // this parity's a-rows fully consumed (all waves)
        const int rb = 16 * ep;   // even -> tiles T0/T2/T4, odd -> T1/T3/T5
        s_buf[swz(rb + 0  + ng, c)] = f2bf(aV[0]);
        s_buf[swz(rb + 4  + ng, c)] = f2bf(aV[1]);
        s_buf[swz(rb + 8  + ng, c)] = f2bf(aV[2]);
        s_buf[swz(rb + 12 + ng, c)] = f2bf(aV[3]);
        s_buf[swz(rb + 32 + ng, c)] = f2bf(ard);
        s_buf[swz(rb + 36 + ng, c)] = f2bf(arr[0]);
        s_buf[swz(rb + 40 + ng, c)] = f2bf(arr[1]);
        s_buf[swz(rb + 44 + ng, c)] = f2bf(arr[2]);
        s_buf[swz(rb + 64 + ng, c)] = f2bf(aV[4]);
        s_buf[swz(rb + 68 + ng, c)] = f2bf(aV[5]);
        s_buf[swz(rb + 72 + ng, c)] = f2bf(aV[6]);
        s_buf[swz(rb + 76 + ng, c)] = f2bf(aV[7]);
        s_buf[swz(96 + 4 * ep + ng, c)] = f2bf(aV[8]);
    }
    __syncthreads();

    // ---------- phase 5: MFMA projection, 3 passes (<=12 AGPR each) -------
    {
        const int d = 16 * w + ln15;
        float* ob = out + (size_t)n0 * 1152 + d;
    #define LDA(tb) (*(const bh8*)&s_buf[((tb) + ln15) * 128 + ((((lq + 4 * ks)) ^ (((tb) + ln15) & 7)) << 3)])
    #define LDB(m)  (*(const bh8*)&wcT[(m) * 16384 + (16 * w + ln15) * 128 + lq * 8 + 32 * ks])
        // pass A: l = 0 (aV0@W0 + ard@Wd), even + odd
        {
            fv4 aE = {0.f, 0.f, 0.f, 0.f};
            fv4 aO = {0.f, 0.f, 0.f, 0.f};
            #pragma unroll
            for (int ks = 0; ks < 4; ++ks) {
                const bh8 W0 = LDB(0), Wd = LDB(1);
                aE = MFMA(LDA(0),  W0, aE);  aE = MFMA(LDA(32), Wd, aE);
                aO = MFMA(LDA(16), W0, aO);  aO = MFMA(LDA(48), Wd, aO);
            }
            const float pb = proj_b[d];
            #pragma unroll
            for (int r = 0; r < 4; ++r) {
                const int rt = lq * 4 + r;
                if (rt < 4) {
                    ob[(size_t)(2 * rt) * 1152]     = aE[r] + pb;
                    ob[(size_t)(2 * rt + 1) * 1152] = aO[r] + pb;
                }
            }
        }
        // pass B: l = 1..3 (aV1-3@W1 + arV0@Wr), even + odd
        {
            fv4 aE = {0.f, 0.f, 0.f, 0.f};
            fv4 aO = {0.f, 0.f, 0.f, 0.f};
            #pragma unroll
            for (int ks = 0; ks < 4; ++ks) {
                const bh8 W1 = LDB(2), Wr = LDB(3);
                aE = MFMA(LDA(0),  W1, aE);  aE = MFMA(LDA(32), Wr, aE);
                aO = MFMA(LDA(16), W1, aO);  aO = MFMA(LDA(48), Wr, aO);
            }
            #pragma unroll
            for (int r = 0; r < 4; ++r) {
                const int rt = lq * 4 + r;
                if (rt >= 4) {
                    const int l = rt >> 2;       // 1..3
                    const int s = rt & 3;
                    ob[(size_t)(2 * s) * 1152 + l * 128]     = aE[r];
                    ob[(size_t)(2 * s + 1) * 1152 + l * 128] = aO[r];
                }
            }
        }
        // pass C: l = 4..8 (aV4-8@W2), even + odd + l8
        {
            fv4 aE = {0.f, 0.f, 0.f, 0.f};
            fv4 aO = {0.f, 0.f, 0.f, 0.f};
            fv4 aG = {0.f, 0.f, 0.f, 0.f};
            #pragma unroll
            for (int ks = 0; ks < 4; ++ks) {
                const bh8 W2 = LDB(4);
                aE = MFMA(LDA(64), W2, aE);
                aO = MFMA(LDA(80), W2, aO);
                aG = MFMA(LDA(96), W2, aG);
            }
            #pragma unroll
            for (int r = 0; r < 4; ++r) {
                const int rt = lq * 4 + r;
                const int s = rt & 3;
                const int l4 = 4 + (rt >> 2);
                ob[(size_t)(2 * s) * 1152 + l4 * 128]     = aE[r];
                ob[(size_t)(2 * s + 1) * 1152 + l4 * 128] = aO[r];
                if (rt < 4)
                    ob[(size_t)(2 * rt) * 1152 + 8 * 128] = aG[r];
                else if (rt < 8)
                    ob[(size_t)(2 * (rt - 4) + 1) * 1152 + 8 * 128] = aG[r];
            }
        }
    #undef LDA
    #undef LDB
    }
}

extern "C" void kernel_launch(void* const* d_in, const int* in_sizes, int n_in,
                              void* d_out, int out_size, void* d_ws, size_t ws_size,
                              hipStream_t stream)
{
    const float* alpha        = (const float*)d_in[0];
    const float* value        = (const float*)d_in[1];
    const float* x_edge       = (const float*)d_in[2];
    const float* node_pos     = (const float*)d_in[3];
    const float* edge_dis     = (const float*)d_in[4];
    const float* exp_node_pos = (const float*)d_in[5];
    const float* rad_w1       = (const float*)d_in[6];
    const float* rad_b1       = (const float*)d_in[7];
    const float* ln_g         = (const float*)d_in[8];
    const float* ln_b         = (const float*)d_in[9];
    const float* rad_w2       = (const float*)d_in[10];
    const float* rad_b2       = (const float*)d_in[11];
    const float* tp_w_same    = (const float*)d_in[12];
    const float* tp_w_rv0     = (const float*)d_in[13];
    const float* tp_w_rdot    = (const float*)d_in[14];
    const float* proj_w       = (const float*)d_in[15];
    const float* proj_b       = (const float*)d_in[16];
    const int* outcell_index  = (const int*)d_in[17];
    const int* f_sparse_idx   = (const int*)d_in[18];
    float* out = (float*)d_out;
    unsigned short* ws = (unsigned short*)d_ws;

    const int N = in_sizes[0] / (16 * 8);   // 16000
    const int vElems = in_sizes[1];         // N*1152

    prep_kernel<<<656, 128, 0, stream>>>(rad_w1, rad_w2, tp_w_same, tp_w_rv0,
                                         tp_w_rdot, proj_w, ws);

    const size_t need = ((size_t)106496 + (size_t)vElems) * 2;
    if (ws_size >= need) {
        unsigned short* vhf = ws + 106496;
        const int n8 = vElems / 8;
        conv_value_kernel<<<(n8 + 255) / 256, 256, 0, stream>>>(value, vhf, n8);
        foa_main<1><<<N / NB, BLK, 0, stream>>>(alpha, value, x_edge, node_pos, edge_dis,
                                                exp_node_pos, rad_b1, ln_g, ln_b, rad_b2,
                                                proj_b, ws, vhf, outcell_index,
                                                f_sparse_idx, out);
    } else {
        foa_main<0><<<N / NB, BLK, 0, stream>>>(alpha, value, x_edge, node_pos, edge_dis,
                                                exp_node_pos, rad_b1, ln_g, ln_b, rad_b2,
                                                proj_b, ws, ws, outcell_index,
                                                f_sparse_idx, out);
    }
}

// Round 12
// 298.418 us; speedup vs baseline: 1.1003x; 1.1003x over previous
//
#include <hip/hip_runtime.h>
#include <hip/hip_fp16.h>

typedef __attribute__((ext_vector_type(8))) short bh8;
typedef __attribute__((ext_vector_type(4))) float fv4;

#define NB 8
#define EB 128
#define BLK 512

#define MFMA(a, b, c) __builtin_amdgcn_mfma_f32_16x16x32_bf16((a), (b), (c), 0, 0, 0)

__device__ __forceinline__ unsigned short f2bf(float x) {
    unsigned int u = __float_as_uint(x);
    u += 0x7fffu + ((u >> 16) & 1u);
    return (unsigned short)(u >> 16);
}
__device__ __forceinline__ float bf2f(unsigned short h) {
    return __uint_as_float(((unsigned int)h) << 16);
}
__device__ __forceinline__ int swz(int row, int col) {
    return row * 128 + ((((col >> 3) ^ (row & 7)) << 3) | (col & 7));
}

// ws layout (ushort): [0,8192) w1T; [8192,24576) w2T; [24576,106496) wcT;
// [106496,+vN*1152) vhf fp16; then a_g [N*16][128] bf16; then tpin_g [N][13][128] bf16
__global__ void prep_kernel(
    const float* __restrict__ rad_w1, const float* __restrict__ rad_w2,
    const float* __restrict__ tp_w_same, const float* __restrict__ tp_w_rv0,
    const float* __restrict__ tp_w_rdot, const float* __restrict__ proj_w,
    unsigned short* __restrict__ ws)
{
    unsigned short* w1T = ws;
    unsigned short* w2T = ws + 8192;
    unsigned short* wcT = ws + 24576;
    const int b = blockIdx.x, t = threadIdx.x;
    if (b < 640) {
        const int m = b >> 7, d = b & 127;
        const float* A; const float* B;
        if (m == 0)      { A = tp_w_same;         B = proj_w; }
        else if (m == 1) { A = tp_w_rdot;         B = proj_w; }
        else if (m == 2) { A = tp_w_same + 16384; B = proj_w + 16384; }
        else if (m == 3) { A = tp_w_rv0;          B = proj_w + 16384; }
        else             { A = tp_w_same + 32768; B = proj_w + 32768; }
        __shared__ float Bs[128];
        Bs[t] = B[t * 128 + d];
        __syncthreads();
        float acc = 0.f;
        const float* Ar = A + t * 128;
        #pragma unroll 4
        for (int x = 0; x < 128; ++x) acc = fmaf(Ar[x], Bs[x], acc);
        wcT[m * 16384 + d * 128 + t] = f2bf(acc);
    } else {
        const int bb = b - 640;
        #pragma unroll
        for (int i = 0; i < 12; ++i) {
            const int idx = bb * 1536 + i * 128 + t;
            if (idx < 8192) {
                const int j = idx >> 6, c = idx & 63;
                w1T[idx] = f2bf(rad_w1[c * 128 + j]);
            } else if (idx < 24576) {
                const int i2 = idx - 8192;
                const int j = i2 >> 7, c = i2 & 127;
                w2T[i2] = f2bf(rad_w2[c * 128 + j]);
            }
        }
    }
}

__global__ __launch_bounds__(256) void conv_value_kernel(
    const float* __restrict__ v, unsigned short* __restrict__ o, int n8)
{
    const int i = blockIdx.x * 256 + threadIdx.x;
    if (i >= n8) return;
    const float4 a = *(const float4*)(v + (size_t)i * 8);
    const float4 b = *(const float4*)(v + (size_t)i * 8 + 4);
    uint4 r;
    r.x = (unsigned int)__half_as_ushort(__float2half_rn(a.x)) |
          ((unsigned int)__half_as_ushort(__float2half_rn(a.y)) << 16);
    r.y = (unsigned int)__half_as_ushort(__float2half_rn(a.z)) |
          ((unsigned int)__half_as_ushort(__float2half_rn(a.w)) << 16);
    r.z = (unsigned int)__half_as_ushort(__float2half_rn(b.x)) |
          ((unsigned int)__half_as_ushort(__float2half_rn(b.y)) << 16);
    r.w = (unsigned int)__half_as_ushort(__float2half_rn(b.z)) |
          ((unsigned int)__half_as_ushort(__float2half_rn(b.w)) << 16);
    *(uint4*)(o + (size_t)i * 8) = r;
}

// ================= kernel A: radial MLP -> a (bf16, unswizzled) ===========
__global__ __launch_bounds__(BLK, 4) void foa_mlp(
    const float* __restrict__ alpha, const float* __restrict__ x_edge,
    const float* __restrict__ edge_dis,
    const float* __restrict__ rad_b1, const float* __restrict__ ln_g,
    const float* __restrict__ ln_b, const float* __restrict__ rad_b2,
    const unsigned short* __restrict__ ws,
    unsigned short* __restrict__ a_g)       // [N*16][128] bf16
{
    __shared__ __align__(16) unsigned short s_buf[16384];   // 128 x 128
    __shared__ float s_alpha[1024];
    __shared__ float s_invd[EB];

    const unsigned short* w1T = ws;
    const unsigned short* w2T = ws + 8192;

    const int t = threadIdx.x;
    const int e0 = blockIdx.x * EB;
    const int lane = t & 63, w = t >> 6;
    const int ln15 = lane & 15, lq = lane >> 4;

    if (t < EB) s_invd[t] = 1.0f / (edge_dis[e0 + t] + 1e-8f);
    s_alpha[t]       = alpha[(size_t)e0 * 8 + t];
    s_alpha[t + 512] = alpha[(size_t)e0 * 8 + 512 + t];
    __syncthreads();

    // phase 2: GEMM1 + LN + SiLU (wave-private rows, no barrier after)
    {
        bh8 af0, af1;
        {
            const float* xp = x_edge + ((size_t)(e0 + 16 * w + ln15)) * 64 + lq * 8;
            const float4 u0 = *(const float4*)(xp);
            const float4 u1 = *(const float4*)(xp + 4);
            const float4 u2 = *(const float4*)(xp + 32);
            const float4 u3 = *(const float4*)(xp + 36);
            af0[0] = (short)f2bf(u0.x); af0[1] = (short)f2bf(u0.y);
            af0[2] = (short)f2bf(u0.z); af0[3] = (short)f2bf(u0.w);
            af0[4] = (short)f2bf(u1.x); af0[5] = (short)f2bf(u1.y);
            af0[6] = (short)f2bf(u1.z); af0[7] = (short)f2bf(u1.w);
            af1[0] = (short)f2bf(u2.x); af1[1] = (short)f2bf(u2.y);
            af1[2] = (short)f2bf(u2.z); af1[3] = (short)f2bf(u2.w);
            af1[4] = (short)f2bf(u3.x); af1[5] = (short)f2bf(u3.y);
            af1[6] = (short)f2bf(u3.z); af1[7] = (short)f2bf(u3.w);
        }
        fv4 acc1[8];
        #pragma unroll
        for (int ct = 0; ct < 8; ++ct) { fv4 z = {0.f, 0.f, 0.f, 0.f}; acc1[ct] = z; }
        #pragma unroll
        for (int ct = 0; ct < 8; ++ct) {
            const bh8* bp = (const bh8*)&w1T[(16 * ct + ln15) * 64 + lq * 8];
            acc1[ct] = MFMA(af0, bp[0], acc1[ct]);
            acc1[ct] = MFMA(af1, bp[4], acc1[ct]);
        }
        float b1v[8], gv[8], bvv[8];
        #pragma unroll
        for (int ct = 0; ct < 8; ++ct) {
            b1v[ct] = rad_b1[16 * ct + ln15];
            gv[ct]  = ln_g[16 * ct + ln15];
            bvv[ct] = ln_b[16 * ct + ln15];
        }
        #pragma unroll
        for (int r = 0; r < 4; ++r) {
            float vv[8], s = 0.f, s2 = 0.f;
            #pragma unroll
            for (int ct = 0; ct < 8; ++ct) {
                const float x = acc1[ct][r] + b1v[ct];
                vv[ct] = x; s += x; s2 += x * x;
            }
            s += __shfl_xor(s, 1);  s2 += __shfl_xor(s2, 1);
            s += __shfl_xor(s, 2);  s2 += __shfl_xor(s2, 2);
            s += __shfl_xor(s, 4);  s2 += __shfl_xor(s2, 4);
            s += __shfl_xor(s, 8);  s2 += __shfl_xor(s2, 8);
            const float mu = s * 0.0078125f;
            const float var = s2 * 0.0078125f - mu * mu;
            const float rstd = rsqrtf(var + 1e-5f);
            const int rowg = 16 * w + lq * 4 + r;
            #pragma unroll
            for (int ct = 0; ct < 8; ++ct) {
                float hh = (vv[ct] - mu) * rstd * gv[ct] + bvv[ct];
                hh = hh / (1.f + __expf(-hh));
                s_buf[swz(rowg, 16 * ct + ln15)] = f2bf(hh);
            }
        }
    }

    // phase 3: GEMM2 in-place -> a
    {
        bh8 afr[4];
        const int arow = 16 * w + ln15;
        #pragma unroll
        for (int ks = 0; ks < 4; ++ks) {
            const int acb = (lq + 4 * ks) ^ (arow & 7);
            afr[ks] = *(const bh8*)&s_buf[arow * 128 + (acb << 3)];
        }
        fv4 acc2[8];
        #pragma unroll
        for (int ct = 0; ct < 8; ++ct) { fv4 z = {0.f, 0.f, 0.f, 0.f}; acc2[ct] = z; }
        #pragma unroll
        for (int ks = 0; ks < 4; ++ks) {
            #pragma unroll
            for (int ct = 0; ct < 8; ++ct) {
                const bh8 b = *(const bh8*)&w2T[(16 * ct + ln15) * 128 + lq * 8 + 32 * ks];
                acc2[ct] = MFMA(afr[ks], b, acc2[ct]);
            }
        }
        #pragma unroll
        for (int ct = 0; ct < 8; ++ct) {
            const float b2 = rad_b2[16 * ct + ln15];
            #pragma unroll
            for (int r = 0; r < 4; ++r) {
                const int e = 16 * w + lq * 4 + r;
                const float aval = s_alpha[e * 8 + ct] * (acc2[ct][r] + b2) * s_invd[e];
                s_buf[swz(e, 16 * ct + ln15)] = f2bf(aval);
            }
        }
    }
    __syncthreads();

    // copy-out: de-swizzle LDS -> global, coalesced bh8 stores
    unsigned short* dst = a_g + (size_t)blockIdx.x * 16384;
    #pragma unroll
    for (int i = 0; i < 4; ++i) {
        const int chunk = i * BLK + t;          // [0, 2048)
        const int row = chunk >> 4;
        const int grp = chunk & 15;
        const bh8 v = *(const bh8*)&s_buf[row * 128 + ((grp ^ (row & 7)) << 3)];
        *(bh8*)&dst[row * 128 + grp * 8] = v;
    }
}

// ================= kernel B: gather + TP accumulate (no MFMA) =============
// tpin_g slots: 0..3 aV0-3 | 4 ard | 5..7 ar0-2 | 8..11 aV4-7 | 12 aV8
__global__ __launch_bounds__(256) void foa_gather(
    const unsigned short* __restrict__ a_g,   // [N*16][128] bf16
    const unsigned short* __restrict__ vhf,   // [N][9][128] fp16
    const float* __restrict__ node_pos,
    const float* __restrict__ exp_node_pos,
    const int* __restrict__ outcell_index,
    const int* __restrict__ f_sparse_idx,
    unsigned short* __restrict__ tpin_g)      // [N][13][128] bf16
{
    __shared__ int   s_gidx[32];
    __shared__ float s_rE[32][3];
    const int t = threadIdx.x;
    const int n0 = blockIdx.x * 2;
    if (t < 32) {
        const int nn = n0 + (t >> 4);
        const int eidx = f_sparse_idx[nn * 16 + (t & 15)];
        s_gidx[t] = outcell_index[eidx];
        s_rE[t][0] = node_pos[nn * 3 + 0] - exp_node_pos[(size_t)eidx * 3 + 0];
        s_rE[t][1] = node_pos[nn * 3 + 1] - exp_node_pos[(size_t)eidx * 3 + 1];
        s_rE[t][2] = node_pos[nn * 3 + 2] - exp_node_pos[(size_t)eidx * 3 + 2];
    }
    __syncthreads();

    const int c = t & 127;
    const int nl = t >> 7;                 // 0..1
    const int n = n0 + nl;
    float aV[9], arr[3], ard = 0.f;
    #pragma unroll
    for (int l = 0; l < 9; ++l) aV[l] = 0.f;
    arr[0] = 0.f; arr[1] = 0.f; arr[2] = 0.f;

    const unsigned short* ab = a_g + ((size_t)n * 16) * 128 + c;
    #pragma unroll 4
    for (int k = 0; k < 16; ++k) {
        const int e = nl * 16 + k;
        const float av = bf2f(ab[k * 128]);
        const __half* vp = (const __half*)vhf + (size_t)s_gidx[e] * 1152 + c;
        const float v0 = __half2float(vp[0]);
        const float v1 = __half2float(vp[128]);
        const float v2 = __half2float(vp[256]);
        const float v3 = __half2float(vp[384]);
        const float v4 = __half2float(vp[512]);
        const float v5 = __half2float(vp[640]);
        const float v6 = __half2float(vp[768]);
        const float v7 = __half2float(vp[896]);
        const float v8 = __half2float(vp[1024]);
        aV[0] = fmaf(av, v0, aV[0]); aV[1] = fmaf(av, v1, aV[1]);
        aV[2] = fmaf(av, v2, aV[2]); aV[3] = fmaf(av, v3, aV[3]);
        aV[4] = fmaf(av, v4, aV[4]); aV[5] = fmaf(av, v5, aV[5]);
        aV[6] = fmaf(av, v6, aV[6]); aV[7] = fmaf(av, v7, aV[7]);
        aV[8] = fmaf(av, v8, aV[8]);
        const float r0 = s_rE[e][0], r1 = s_rE[e][1], r2 = s_rE[e][2];
        const float w0 = av * v0;
        arr[0] = fmaf(r0, w0, arr[0]);
        arr[1] = fmaf(r1, w0, arr[1]);
        arr[2] = fmaf(r2, w0, arr[2]);
        ard = fmaf(av, fmaf(r0, v1, fmaf(r1, v2, r2 * v3)), ard);
    }
    unsigned short* tp = tpin_g + (size_t)n * 1664 + c;
    tp[0]        = f2bf(aV[0]);
    tp[1 * 128]  = f2bf(aV[1]);
    tp[2 * 128]  = f2bf(aV[2]);
    tp[3 * 128]  = f2bf(aV[3]);
    tp[4 * 128]  = f2bf(ard);
    tp[5 * 128]  = f2bf(arr[0]);
    tp[6 * 128]  = f2bf(arr[1]);
    tp[7 * 128]  = f2bf(arr[2]);
    tp[8 * 128]  = f2bf(aV[4]);
    tp[9 * 128]  = f2bf(aV[5]);
    tp[10 * 128] = f2bf(aV[6]);
    tp[11 * 128] = f2bf(aV[7]);
    tp[12 * 128] = f2bf(aV[8]);
}

// ================= kernel C: MFMA projection ==============================
__global__ __launch_bounds__(BLK, 4) void foa_proj(
    const unsigned short* __restrict__ tpin_g,
    const unsigned short* __restrict__ ws,
    const float* __restrict__ proj_b,
    float* __restrict__ out)
{
    __shared__ __align__(16) unsigned short s_buf[14336];   // 112 rows x 128
    const unsigned short* wcT = ws + 24576;
    const int t = threadIdx.x;
    const int n0 = blockIdx.x * NB;
    const int lane = t & 63, w = t >> 6;
    const int ln15 = lane & 15, lq = lane >> 4;

    ((unsigned int*)&s_buf[104 * 128])[t] = 0u;   // zero rows 104-111
    const unsigned short* src = tpin_g + (size_t)n0 * 1664;
    #pragma unroll
    for (int i = 0; i < 26; ++i) {
        const int idx = i * BLK + t;              // [0, 13312)
        const int nn = idx / 1664;
        const int rem = idx - nn * 1664;
        const int s = rem >> 7, c = rem & 127;
        const int p = nn & 1, g = nn >> 1;
        int row;
        if (s < 4)       row = 16 * p + 4 * s + g;
        else if (s < 8)  row = 32 + 16 * p + 4 * (s - 4) + g;
        else if (s < 12) row = 64 + 16 * p + 4 * (s - 8) + g;
        else             row = 96 + 4 * p + g;
        s_buf[swz(row, c)] = src[idx];
    }
    __syncthreads();

    fv4 aEA, aEB, aEC, aOA, aOB, aOC, aG;
    { fv4 z = {0.f,0.f,0.f,0.f}; aEA=z; aEB=z; aEC=z; aOA=z; aOB=z; aOC=z; aG=z; }
    #pragma unroll
    for (int ks = 0; ks < 4; ++ks) {
        const int cb = lq + 4 * ks;
    #define LDA(tb) (*(const bh8*)&s_buf[((tb) + ln15) * 128 + (((cb) ^ (((tb) + ln15) & 7)) << 3)])
    #define LDB(m)  (*(const bh8*)&wcT[(m) * 16384 + (16 * w + ln15) * 128 + lq * 8 + 32 * ks])
        const bh8 W0 = LDB(0), Wd = LDB(1), W1 = LDB(2), Wr = LDB(3), W2 = LDB(4);
        const bh8 A0 = LDA(0),  A2 = LDA(32);
        aEA = MFMA(A0, W0, aEA);  aEA = MFMA(A2, Wd, aEA);
        aEB = MFMA(A0, W1, aEB);  aEB = MFMA(A2, Wr, aEB);
        const bh8 A1 = LDA(16), A3 = LDA(48);
        aOA = MFMA(A1, W0, aOA);  aOA = MFMA(A3, Wd, aOA);
        aOB = MFMA(A1, W1, aOB);  aOB = MFMA(A3, Wr, aOB);
        aEC = MFMA(LDA(64), W2, aEC);
        aOC = MFMA(LDA(80), W2, aOC);
        aG  = MFMA(LDA(96), W2, aG);
    #undef LDA
    #undef LDB
    }
    const int d = 16 * w + ln15;
    const float pb = proj_b[d];
    float* ob = out + (size_t)n0 * 1152 + d;
    #pragma unroll
    for (int r = 0; r < 4; ++r) {
        const int rt = lq * 4 + r;
        const int s = rt & 3;
        {
            const int l4 = 4 + (rt >> 2);
            ob[(size_t)(2 * s) * 1152 + l4 * 128]     = aEC[r];
            ob[(size_t)(2 * s + 1) * 1152 + l4 * 128] = aOC[r];
        }
        if (rt < 4) {
            ob[(size_t)(2 * rt) * 1152]             = aEA[r] + pb;
            ob[(size_t)(2 * rt + 1) * 1152]         = aOA[r] + pb;
            ob[(size_t)(2 * rt) * 1152 + 8 * 128]   = aG[r];
        } else {
            const int l = rt >> 2;
            ob[(size_t)(2 * s) * 1152 + l * 128]     = aEB[r];
            ob[(size_t)(2 * s + 1) * 1152 + l * 128] = aOB[r];
            if (rt < 8)
                ob[(size_t)(2 * (rt - 4) + 1) * 1152 + 8 * 128] = aG[r];
        }
    }
}

// ================= fallback: R9 fused kernel ==============================
template <int VHALF>
__global__ __launch_bounds__(BLK, 4) void foa_main(
    const float* __restrict__ alpha, const float* __restrict__ value,
    const float* __restrict__ x_edge, const float* __restrict__ node_pos,
    const float* __restrict__ edge_dis, const float* __restrict__ exp_node_pos,
    const float* __restrict__ rad_b1, const float* __restrict__ ln_g,
    const float* __restrict__ ln_b, const float* __restrict__ rad_b2,
    const float* __restrict__ proj_b, const unsigned short* __restrict__ ws,
    const unsigned short* __restrict__ vhf,
    const int* __restrict__ outcell_index, const int* __restrict__ f_sparse_idx,
    float* __restrict__ out)
{
    __shared__ __align__(16) unsigned short s_buf[16384];
    __shared__ float s_alpha[1024];
    __shared__ float s_rE[EB][3];
    __shared__ float s_invd[EB];
    __shared__ int   s_gidx[EB];

    const unsigned short* w1T = ws;
    const unsigned short* w2T = ws + 8192;
    const unsigned short* wcT = ws + 24576;

    const int t = threadIdx.x;
    const int e0 = blockIdx.x * EB;
    const int n0 = blockIdx.x * NB;
    const int lane = t & 63, w = t >> 6;
    const int ln15 = lane & 15, lq = lane >> 4;

    if (t < EB) {
        const int eidx = f_sparse_idx[e0 + t];
        s_gidx[t] = outcell_index[eidx];
        const int nn = n0 + (t >> 4);
        s_rE[t][0] = node_pos[nn * 3 + 0] - exp_node_pos[(size_t)eidx * 3 + 0];
        s_rE[t][1] = node_pos[nn * 3 + 1] - exp_node_pos[(size_t)eidx * 3 + 1];
        s_rE[t][2] = node_pos[nn * 3 + 2] - exp_node_pos[(size_t)eidx * 3 + 2];
        s_invd[t] = 1.0f / (edge_dis[e0 + t] + 1e-8f);
    }
    s_alpha[t]       = alpha[(size_t)e0 * 8 + t];
    s_alpha[t + 512] = alpha[(size_t)e0 * 8 + 512 + t];
    __syncthreads();

    {
        bh8 af0, af1;
        {
            const float* xp = x_edge + ((size_t)(e0 + 16 * w + ln15)) * 64 + lq * 8;
            const float4 u0 = *(const float4*)(xp);
            const float4 u1 = *(const float4*)(xp + 4);
            const float4 u2 = *(const float4*)(xp + 32);
            const float4 u3 = *(const float4*)(xp + 36);
            af0[0] = (short)f2bf(u0.x); af0[1] = (short)f2bf(u0.y);
            af0[2] = (short)f2bf(u0.z); af0[3] = (short)f2bf(u0.w);
            af0[4] = (short)f2bf(u1.x); af0[5] = (short)f2bf(u1.y);
            af0[6] = (short)f2bf(u1.z); af0[7] = (short)f2bf(u1.w);
            af1[0] = (short)f2bf(u2.x); af1[1] = (short)f2bf(u2.y);
            af1[2] = (short)f2bf(u2.z); af1[3] = (short)f2bf(u2.w);
            af1[4] = (short)f2bf(u3.x); af1[5] = (short)f2bf(u3.y);
            af1[6] = (short)f2bf(u3.z); af1[7] = (short)f2bf(u3.w);
        }
        fv4 acc1[8];
        #pragma unroll
        for (int ct = 0; ct < 8; ++ct) { fv4 z = {0.f, 0.f, 0.f, 0.f}; acc1[ct] = z; }
        #pragma unroll
        for (int ct = 0; ct < 8; ++ct) {
            const bh8* bp = (const bh8*)&w1T[(16 * ct + ln15) * 64 + lq * 8];
            acc1[ct] = MFMA(af0, bp[0], acc1[ct]);
            acc1[ct] = MFMA(af1, bp[4], acc1[ct]);
        }
        float b1v[8], gv[8], bvv[8];
        #pragma unroll
        for (int ct = 0; ct < 8; ++ct) {
            b1v[ct] = rad_b1[16 * ct + ln15];
            gv[ct]  = ln_g[16 * ct + ln15];
            bvv[ct] = ln_b[16 * ct + ln15];
        }
        #pragma unroll
        for (int r = 0; r < 4; ++r) {
            float vv[8], s = 0.f, s2 = 0.f;
            #pragma unroll
            for (int ct = 0; ct < 8; ++ct) {
                const float x = acc1[ct][r] + b1v[ct];
                vv[ct] = x; s += x; s2 += x * x;
            }
            s += __shfl_xor(s, 1);  s2 += __shfl_xor(s2, 1);
            s += __shfl_xor(s, 2);  s2 += __shfl_xor(s2, 2);
            s += __shfl_xor(s, 4);  s2 += __shfl_xor(s2, 4);
            s += __shfl_xor(s, 8);  s2 += __shfl_xor(s2, 8);
            const float mu = s * 0.0078125f;
            const float var = s2 * 0.0078125f - mu * mu;
            const float rstd = rsqrtf(var + 1e-5f);
            const int rowg = 16 * w + lq * 4 + r;
            #pragma unroll
            for (int ct = 0; ct < 8; ++ct) {
                float hh = (vv[ct] - mu) * rstd * gv[ct] + bvv[ct];
                hh = hh / (1.f + __expf(-hh));
                s_buf[swz(rowg, 16 * ct + ln15)] = f2bf(hh);
            }
        }
    }

    {
        bh8 afr[4];
        const int arow = 16 * w + ln15;
        #pragma unroll
        for (int ks = 0; ks < 4; ++ks) {
            const int acb = (lq + 4 * ks) ^ (arow & 7);
            afr[ks] = *(const bh8*)&s_buf[arow * 128 + (acb << 3)];
        }
        fv4 acc2[8];
        #pragma unroll
        for (int ct = 0; ct < 8; ++ct) { fv4 z = {0.f, 0.f, 0.f, 0.f}; acc2[ct] = z; }
        #pragma unroll
        for (int ks = 0; ks < 4; ++ks) {
            #pragma unroll
            for (int ct = 0; ct < 8; ++ct) {
                const bh8 b = *(const bh8*)&w2T[(16 * ct + ln15) * 128 + lq * 8 + 32 * ks];
                acc2[ct] = MFMA(afr[ks], b, acc2[ct]);
            }
        }
        #pragma unroll
        for (int ct = 0; ct < 8; ++ct) {
            const float b2 = rad_b2[16 * ct + ln15];
            #pragma unroll
            for (int r = 0; r < 4; ++r) {
                const int e = 16 * w + lq * 4 + r;
                const float aval = s_alpha[e * 8 + ct] * (acc2[ct][r] + b2) * s_invd[e];
                s_buf[swz(e, 16 * ct + ln15)] = f2bf(aval);
            }
        }
    }
    __syncthreads();

    const int c = t & 127;
    const int ng = t >> 7;
    float aV[9], arr[3], ard;

    #pragma unroll
    for (int ep = 0; ep < 2; ++ep) {
        #pragma unroll
        for (int l = 0; l < 9; ++l) aV[l] = 0.f;
        arr[0] = 0.f; arr[1] = 0.f; arr[2] = 0.f; ard = 0.f;
        #pragma unroll 4
        for (int k = 0; k < 16; ++k) {
            const int e = 32 * ng + 16 * ep + k;
            const float av = bf2f(s_buf[swz(e, c)]);
            float v0, v1, v2, v3, v4, v5, v6, v7, v8;
            if constexpr (VHALF) {
                const __half* vp = (const __half*)vhf + (size_t)s_gidx[e] * 1152 + c;
                v0 = __half2float(vp[0]);    v1 = __half2float(vp[128]);
                v2 = __half2float(vp[256]);  v3 = __half2float(vp[384]);
                v4 = __half2float(vp[512]);  v5 = __half2float(vp[640]);
                v6 = __half2float(vp[768]);  v7 = __half2float(vp[896]);
                v8 = __half2float(vp[1024]);
            } else {
                const float* vp = value + (size_t)s_gidx[e] * 1152 + c;
                v0 = vp[0];    v1 = vp[128];  v2 = vp[256];
                v3 = vp[384];  v4 = vp[512];  v5 = vp[640];
                v6 = vp[768];  v7 = vp[896];  v8 = vp[1024];
            }
            aV[0] = fmaf(av, v0, aV[0]); aV[1] = fmaf(av, v1, aV[1]);
            aV[2] = fmaf(av, v2, aV[2]); aV[3] = fmaf(av, v3, aV[3]);
            aV[4] = fmaf(av, v4, aV[4]); aV[5] = fmaf(av, v5, aV[5]);
            aV[6] = fmaf(av, v6, aV[6]); aV[7] = fmaf(av, v7, aV[7]);
            aV[8] = fmaf(av, v8, aV[8]);
            const float r0 = s_rE[e][0], r1 = s_rE[e][1], r2 = s_rE[e][2];
            const float w0 = av * v0;
            arr[0] = fmaf(r0, w0, arr[0]);
            arr[1] = fmaf(r1, w0, arr[1]);
            arr[2] = fmaf(r2, w0, arr[2]);
            ard = fmaf(av, fmaf(r0, v1, fmaf(r1, v2, r2 * v3)), ard);
        }
        __syncthreads();
        const int rb = 16 * ep;
        s_buf[swz(rb + 0  + ng, c)] = f2bf(aV[0]);
        s_buf[swz(rb + 4  + ng, c)] = f2bf(aV[1]);
        s_buf[swz(rb + 8  + ng, c)] = f2bf(aV[2]);
        s_buf[swz(rb + 12 + ng, c)] = f2bf(aV[3]);
        s_buf[swz(rb + 32 + ng, c)] = f2bf(ard);
        s_buf[swz(rb + 36 + ng, c)] = f2bf(arr[0]);
        s_buf[swz(rb + 40 + ng, c)] = f2bf(arr[1]);
        s_buf[swz(rb + 44 + ng, c)] = f2bf(arr[2]);
        s_buf[swz(rb + 64 + ng, c)] = f2bf(aV[4]);
        s_buf[swz(rb + 68 + ng, c)] = f2bf(aV[5]);
        s_buf[swz(rb + 72 + ng, c)] = f2bf(aV[6]);
        s_buf[swz(rb + 76 + ng, c)] = f2bf(aV[7]);
        s_buf[swz(96 + 4 * ep + ng, c)] = f2bf(aV[8]);
    }
    __syncthreads();

    {
        fv4 aEA, aEB, aEC, aOA, aOB, aOC, aG;
        { fv4 z = {0.f,0.f,0.f,0.f}; aEA=z; aEB=z; aEC=z; aOA=z; aOB=z; aOC=z; aG=z; }
        #pragma unroll
        for (int ks = 0; ks < 4; ++ks) {
            const int cb = lq + 4 * ks;
        #define LDA(tb) (*(const bh8*)&s_buf[((tb) + ln15) * 128 + (((cb) ^ (((tb) + ln15) & 7)) << 3)])
        #define LDB(m)  (*(const bh8*)&wcT[(m) * 16384 + (16 * w + ln15) * 128 + lq * 8 + 32 * ks])
            const bh8 W0 = LDB(0), Wd = LDB(1), W1 = LDB(2), Wr = LDB(3), W2 = LDB(4);
            const bh8 A0 = LDA(0),  A2 = LDA(32);
            aEA = MFMA(A0, W0, aEA);  aEA = MFMA(A2, Wd, aEA);
            aEB = MFMA(A0, W1, aEB);  aEB = MFMA(A2, Wr, aEB);
            const bh8 A1 = LDA(16), A3 = LDA(48);
            aOA = MFMA(A1, W0, aOA);  aOA = MFMA(A3, Wd, aOA);
            aOB = MFMA(A1, W1, aOB);  aOB = MFMA(A3, Wr, aOB);
            aEC = MFMA(LDA(64), W2, aEC);
            aOC = MFMA(LDA(80), W2, aOC);
            aG  = MFMA(LDA(96), W2, aG);
        #undef LDA
        #undef LDB
        }
        const int d = 16 * w + ln15;
        const float pb = proj_b[d];
        float* ob = out + (size_t)n0 * 1152 + d;
        #pragma unroll
        for (int r = 0; r < 4; ++r) {
            const int rt = lq * 4 + r;
            const int s = rt & 3;
            {
                const int l4 = 4 + (rt >> 2);
                ob[(size_t)(2 * s) * 1152 + l4 * 128]     = aEC[r];
                ob[(size_t)(2 * s + 1) * 1152 + l4 * 128] = aOC[r];
            }
            if (rt < 4) {
                ob[(size_t)(2 * rt) * 1152]             = aEA[r] + pb;
                ob[(size_t)(2 * rt + 1) * 1152]         = aOA[r] + pb;
                ob[(size_t)(2 * rt) * 1152 + 8 * 128]   = aG[r];
            } else {
                const int l = rt >> 2;
                ob[(size_t)(2 * s) * 1152 + l * 128]     = aEB[r];
                ob[(size_t)(2 * s + 1) * 1152 + l * 128] = aOB[r];
                if (rt < 8)
                    ob[(size_t)(2 * (rt - 4) + 1) * 1152 + 8 * 128] = aG[r];
            }
        }
    }
}

extern "C" void kernel_launch(void* const* d_in, const int* in_sizes, int n_in,
                              void* d_out, int out_size, void* d_ws, size_t ws_size,
                              hipStream_t stream)
{
    const float* alpha        = (const float*)d_in[0];
    const float* value        = (const float*)d_in[1];
    const float* x_edge       = (const float*)d_in[2];
    const float* node_pos     = (const float*)d_in[3];
    const float* edge_dis     = (const float*)d_in[4];
    const float* exp_node_pos = (const float*)d_in[5];
    const float* rad_w1       = (const float*)d_in[6];
    const float* rad_b1       = (const float*)d_in[7];
    const float* ln_g         = (const float*)d_in[8];
    const float* ln_b         = (const float*)d_in[9];
    const float* rad_w2       = (const float*)d_in[10];
    const float* rad_b2       = (const float*)d_in[11];
    const float* tp_w_same    = (const float*)d_in[12];
    const float* tp_w_rv0     = (const float*)d_in[13];
    const float* tp_w_rdot    = (const float*)d_in[14];
    const float* proj_w       = (const float*)d_in[15];
    const float* proj_b       = (const float*)d_in[16];
    const int* outcell_index  = (const int*)d_in[17];
    const int* f_sparse_idx   = (const int*)d_in[18];
    float* out = (float*)d_out;
    unsigned short* ws = (unsigned short*)d_ws;

    const int N = in_sizes[0] / (16 * 8);   // 16000
    const int vElems = in_sizes[1];         // vN*1152
    const int vN = vElems / 1152;

    prep_kernel<<<656, 128, 0, stream>>>(rad_w1, rad_w2, tp_w_same, tp_w_rv0,
                                         tp_w_rdot, proj_w, ws);

    const size_t base = 106496;
    const size_t offV = base;
    const size_t offA = offV + (size_t)vN * 1152;
    const size_t offT = offA + (size_t)N * 16 * 128;
    const size_t endT = offT + (size_t)N * 13 * 128;

    if (ws_size >= endT * 2) {
        unsigned short* vhf    = ws + offV;
        unsigned short* a_g    = ws + offA;
        unsigned short* tpin_g = ws + offT;
        const int n8 = vElems / 8;
        conv_value_kernel<<<(n8 + 255) / 256, 256, 0, stream>>>(value, vhf, n8);
        foa_mlp<<<N / NB, BLK, 0, stream>>>(alpha, x_edge, edge_dis, rad_b1, ln_g,
                                            ln_b, rad_b2, ws, a_g);
        foa_gather<<<N / 2, 256, 0, stream>>>(a_g, vhf, node_pos, exp_node_pos,
                                              outcell_index, f_sparse_idx, tpin_g);
        foa_proj<<<N / NB, BLK, 0, stream>>>(tpin_g, ws, proj_b, out);
    } else if (ws_size >= (offA) * 2) {
        unsigned short* vhf = ws + offV;
        const int n8 = vElems / 8;
        conv_value_kernel<<<(n8 + 255) / 256, 256, 0, stream>>>(value, vhf, n8);
        foa_main<1><<<N / NB, BLK, 0, stream>>>(alpha, value, x_edge, node_pos, edge_dis,
                                                exp_node_pos, rad_b1, ln_g, ln_b, rad_b2,
                                                proj_b, ws, vhf, outcell_index,
                                                f_sparse_idx, out);
    } else {
        foa_main<0><<<N / NB, BLK, 0, stream>>>(alpha, value, x_edge, node_pos, edge_dis,
                                                exp_node_pos, rad_b1, ln_g, ln_b, rad_b2,
                                                proj_b, ws, ws, outcell_index,
                                                f_sparse_idx, out);
    }
}

// Round 13
// 183.033 us; speedup vs baseline: 1.7939x; 1.6304x over previous
//
#include <hip/hip_runtime.h>
#include <hip/hip_fp16.h>

typedef __attribute__((ext_vector_type(8))) short bh8;
typedef __attribute__((ext_vector_type(4))) float fv4;

#define NB 8
#define EB 128
#define BLK 512

#define MFMA(a, b, c) __builtin_amdgcn_mfma_f32_16x16x32_bf16((a), (b), (c), 0, 0, 0)

__device__ __forceinline__ unsigned short f2bf(float x) {
    unsigned int u = __float_as_uint(x);
    u += 0x7fffu + ((u >> 16) & 1u);
    return (unsigned short)(u >> 16);
}
__device__ __forceinline__ float bf2f(unsigned short h) {
    return __uint_as_float(((unsigned int)h) << 16);
}
// element index into a row-major [*][128] bf16 LDS tile, 8-elem XOR swizzle
__device__ __forceinline__ int swz(int row, int col) {
    return row * 128 + ((((col >> 3) ^ (row & 7)) << 3) | (col & 7));
}

// ws layout (ushort): [0,8192) w1T[128][64]; [8192,24576) w2T[128][128];
// [24576,106496) wcT[5][128][128]; [106496, +N*1152) vhf (fp16 value)
__global__ void prep_kernel(
    const float* __restrict__ rad_w1, const float* __restrict__ rad_w2,
    const float* __restrict__ tp_w_same, const float* __restrict__ tp_w_rv0,
    const float* __restrict__ tp_w_rdot, const float* __restrict__ proj_w,
    unsigned short* __restrict__ ws)
{
    unsigned short* w1T = ws;
    unsigned short* w2T = ws + 8192;
    unsigned short* wcT = ws + 24576;
    const int b = blockIdx.x, t = threadIdx.x;
    if (b < 640) {
        const int m = b >> 7, d = b & 127;
        const float* A; const float* B;
        if (m == 0)      { A = tp_w_same;         B = proj_w; }
        else if (m == 1) { A = tp_w_rdot;         B = proj_w; }
        else if (m == 2) { A = tp_w_same + 16384; B = proj_w + 16384; }
        else if (m == 3) { A = tp_w_rv0;          B = proj_w + 16384; }
        else             { A = tp_w_same + 32768; B = proj_w + 32768; }
        __shared__ float Bs[128];
        Bs[t] = B[t * 128 + d];
        __syncthreads();
        float acc = 0.f;
        const float* Ar = A + t * 128;
        #pragma unroll 4
        for (int x = 0; x < 128; ++x) acc = fmaf(Ar[x], Bs[x], acc);
        wcT[m * 16384 + d * 128 + t] = f2bf(acc);
    } else {
        const int bb = b - 640;
        #pragma unroll
        for (int i = 0; i < 12; ++i) {
            const int idx = bb * 1536 + i * 128 + t;
            if (idx < 8192) {
                const int j = idx >> 6, c = idx & 63;
                w1T[idx] = f2bf(rad_w1[c * 128 + j]);
            } else if (idx < 24576) {
                const int i2 = idx - 8192;
                const int j = i2 >> 7, c = i2 & 127;
                w2T[i2] = f2bf(rad_w2[c * 128 + j]);
            }
        }
    }
}

__global__ __launch_bounds__(256) void conv_value_kernel(
    const float* __restrict__ v, unsigned short* __restrict__ o, int n8)
{
    const int i = blockIdx.x * 256 + threadIdx.x;
    if (i >= n8) return;
    const float4 a = *(const float4*)(v + (size_t)i * 8);
    const float4 b = *(const float4*)(v + (size_t)i * 8 + 4);
    uint4 r;
    r.x = (unsigned int)__half_as_ushort(__float2half_rn(a.x)) |
          ((unsigned int)__half_as_ushort(__float2half_rn(a.y)) << 16);
    r.y = (unsigned int)__half_as_ushort(__float2half_rn(a.z)) |
          ((unsigned int)__half_as_ushort(__float2half_rn(a.w)) << 16);
    r.z = (unsigned int)__half_as_ushort(__float2half_rn(b.x)) |
          ((unsigned int)__half_as_ushort(__float2half_rn(b.y)) << 16);
    r.w = (unsigned int)__half_as_ushort(__float2half_rn(b.z)) |
          ((unsigned int)__half_as_ushort(__float2half_rn(b.w)) << 16);
    *(uint4*)(o + (size_t)i * 8) = r;
}

// tpin layout inside the 128-row a-buffer (each tile 16 rows, slot s=ng):
//  T0(r0):  aV0 e | aV1 e | aV2 e | aV3 e      (e = even nodes 2s)
//  T1(r16): aV0 o | aV1 o | aV2 o | aV3 o      (o = odd nodes 2s+1)
//  T2(r32): ard e | ar0 e | ar1 e | ar2 e
//  T3(r48): ard o | ar0 o | ar1 o | ar2 o
//  T4(r64): aV4 e | aV5 e | aV6 e | aV7 e
//  T5(r80): aV4 o | aV5 o | aV6 o | aV7 o
//  T6(r96): aV8 e (0-3) | aV8 o (4-7) | stale (8-15, ignored)
template <int VHALF>
__global__ __launch_bounds__(BLK, 4) void foa_main(
    const float* __restrict__ alpha,        // [N*K*8]
    const float* __restrict__ value,        // [N][9][128] fp32 (fallback)
    const float* __restrict__ x_edge,       // [N*K][64]
    const float* __restrict__ node_pos,     // [N][3]
    const float* __restrict__ edge_dis,     // [N*K]
    const float* __restrict__ exp_node_pos, // [M][3]
    const float* __restrict__ rad_b1, const float* __restrict__ ln_g,
    const float* __restrict__ ln_b, const float* __restrict__ rad_b2,
    const float* __restrict__ proj_b,
    const unsigned short* __restrict__ ws,
    const unsigned short* __restrict__ vhf, // fp16 value table
    const int* __restrict__ outcell_index,
    const int* __restrict__ f_sparse_idx,
    float* __restrict__ out)                // [N][9][128]
{
    // s_buf: hbuf (ph2) -> a in-place (ph3) -> tpin (parity-split ph4-5)
    // s_w2: w2T staged+swizzled (ph3 B-operands from LDS, not contended L2)
    __shared__ __align__(16) unsigned short s_buf[16384];   // 128 rows x 128
    __shared__ __align__(16) unsigned short s_w2[16384];    // 128 rows x 128
    __shared__ float s_alpha[1024];
    __shared__ float s_rE[EB][3];
    __shared__ float s_invd[EB];
    __shared__ int   s_gidx[EB];

    const unsigned short* w1T = ws;
    const unsigned short* w2T = ws + 8192;
    const unsigned short* wcT = ws + 24576;

    const int t = threadIdx.x;
    const int e0 = blockIdx.x * EB;
    const int n0 = blockIdx.x * NB;
    const int lane = t & 63, w = t >> 6;
    const int ln15 = lane & 15, lq = lane >> 4;

    // ---------- phase 0: per-edge metadata + stage w2T into LDS ----------
    if (t < EB) {
        const int eidx = f_sparse_idx[e0 + t];
        s_gidx[t] = outcell_index[eidx];
        const int nn = n0 + (t >> 4);
        s_rE[t][0] = node_pos[nn * 3 + 0] - exp_node_pos[(size_t)eidx * 3 + 0];
        s_rE[t][1] = node_pos[nn * 3 + 1] - exp_node_pos[(size_t)eidx * 3 + 1];
        s_rE[t][2] = node_pos[nn * 3 + 2] - exp_node_pos[(size_t)eidx * 3 + 2];
        s_invd[t] = 1.0f / (edge_dis[e0 + t] + 1e-8f);
    }
    s_alpha[t]       = alpha[(size_t)e0 * 8 + t];
    s_alpha[t + 512] = alpha[(size_t)e0 * 8 + 512 + t];
    #pragma unroll
    for (int i = 0; i < 4; ++i) {
        const int chunk = i * BLK + t;        // 2048 chunks x 8 ushorts
        const int row = chunk >> 4, grp = chunk & 15;
        const bh8 v = *(const bh8*)&w2T[row * 128 + grp * 8];
        *(bh8*)&s_w2[row * 128 + ((grp ^ (row & 7)) << 3)] = v;
    }
    __syncthreads();

    // ---------- phase 2: GEMM1 [128,64]@w1 -> LN -> SiLU -> s_buf (bf16) --
    // wave w touches ONLY rows [16w,16w+16) here and in phase 3 -> no barrier
    {
        bh8 af0, af1;
        {
            const float* xp = x_edge + ((size_t)(e0 + 16 * w + ln15)) * 64 + lq * 8;
            const float4 u0 = *(const float4*)(xp);
            const float4 u1 = *(const float4*)(xp + 4);
            const float4 u2 = *(const float4*)(xp + 32);
            const float4 u3 = *(const float4*)(xp + 36);
            af0[0] = (short)f2bf(u0.x); af0[1] = (short)f2bf(u0.y);
            af0[2] = (short)f2bf(u0.z); af0[3] = (short)f2bf(u0.w);
            af0[4] = (short)f2bf(u1.x); af0[5] = (short)f2bf(u1.y);
            af0[6] = (short)f2bf(u1.z); af0[7] = (short)f2bf(u1.w);
            af1[0] = (short)f2bf(u2.x); af1[1] = (short)f2bf(u2.y);
            af1[2] = (short)f2bf(u2.z); af1[3] = (short)f2bf(u2.w);
            af1[4] = (short)f2bf(u3.x); af1[5] = (short)f2bf(u3.y);
            af1[6] = (short)f2bf(u3.z); af1[7] = (short)f2bf(u3.w);
        }
        fv4 acc1[8];
        #pragma unroll
        for (int ct = 0; ct < 8; ++ct) { fv4 z = {0.f, 0.f, 0.f, 0.f}; acc1[ct] = z; }
        #pragma unroll
        for (int ct = 0; ct < 8; ++ct) {
            const bh8* bp = (const bh8*)&w1T[(16 * ct + ln15) * 64 + lq * 8];
            acc1[ct] = MFMA(af0, bp[0], acc1[ct]);
            acc1[ct] = MFMA(af1, bp[4], acc1[ct]);
        }
        float b1v[8], gv[8], bvv[8];
        #pragma unroll
        for (int ct = 0; ct < 8; ++ct) {
            b1v[ct] = rad_b1[16 * ct + ln15];
            gv[ct]  = ln_g[16 * ct + ln15];
            bvv[ct] = ln_b[16 * ct + ln15];
        }
        #pragma unroll
        for (int r = 0; r < 4; ++r) {
            float vv[8], s = 0.f, s2 = 0.f;
            #pragma unroll
            for (int ct = 0; ct < 8; ++ct) {
                const float x = acc1[ct][r] + b1v[ct];
                vv[ct] = x; s += x; s2 += x * x;
            }
            s += __shfl_xor(s, 1);  s2 += __shfl_xor(s2, 1);
            s += __shfl_xor(s, 2);  s2 += __shfl_xor(s2, 2);
            s += __shfl_xor(s, 4);  s2 += __shfl_xor(s2, 4);
            s += __shfl_xor(s, 8);  s2 += __shfl_xor(s2, 8);
            const float mu = s * 0.0078125f;
            const float var = s2 * 0.0078125f - mu * mu;
            const float rstd = rsqrtf(var + 1e-5f);
            const int rowg = 16 * w + lq * 4 + r;
            #pragma unroll
            for (int ct = 0; ct < 8; ++ct) {
                float hh = (vv[ct] - mu) * rstd * gv[ct] + bvv[ct];
                hh = hh / (1.f + __expf(-hh));
                s_buf[swz(rowg, 16 * ct + ln15)] = f2bf(hh);
            }
        }
    }
    // NO barrier: phase 3 reads/writes only this wave's rows

    // ---------- phase 3: GEMM2 in-place, B-frags from LDS -> a (bf16) -----
    {
        bh8 afr[4];
        const int arow = 16 * w + ln15;
        #pragma unroll
        for (int ks = 0; ks < 4; ++ks) {
            const int acb = (lq + 4 * ks) ^ (arow & 7);
            afr[ks] = *(const bh8*)&s_buf[arow * 128 + (acb << 3)];
        }
        fv4 acc2[8];
        #pragma unroll
        for (int ct = 0; ct < 8; ++ct) { fv4 z = {0.f, 0.f, 0.f, 0.f}; acc2[ct] = z; }
        #pragma unroll
        for (int ks = 0; ks < 4; ++ks) {
            #pragma unroll
            for (int ct = 0; ct < 8; ++ct) {
                const int brow = 16 * ct + ln15;
                const bh8 b = *(const bh8*)&s_w2[brow * 128 +
                                  (((lq + 4 * ks) ^ (brow & 7)) << 3)];
                acc2[ct] = MFMA(afr[ks], b, acc2[ct]);
            }
        }
        #pragma unroll
        for (int ct = 0; ct < 8; ++ct) {
            const float b2 = rad_b2[16 * ct + ln15];
            #pragma unroll
            for (int r = 0; r < 4; ++r) {
                const int e = 16 * w + lq * 4 + r;
                const float aval = s_alpha[e * 8 + ct] * (acc2[ct][r] + b2) * s_invd[e];
                s_buf[swz(e, 16 * ct + ln15)] = f2bf(aval);
            }
        }
    }
    __syncthreads();

    // ---------- phase 4: parity-split gather (13 accumulators max) --------
    const int c = t & 127;
    const int ng = t >> 7;
    float aV[9], arr[3], ard;

    #pragma unroll
    for (int ep = 0; ep < 2; ++ep) {
        #pragma unroll
        for (int l = 0; l < 9; ++l) aV[l] = 0.f;
        arr[0] = 0.f; arr[1] = 0.f; arr[2] = 0.f; ard = 0.f;
        #pragma unroll 4
        for (int k = 0; k < 16; ++k) {
            const int e = 32 * ng + 16 * ep + k;
            const float av = bf2f(s_buf[swz(e, c)]);
            float v0, v1, v2, v3, v4, v5, v6, v7, v8;
            if constexpr (VHALF) {
                const __half* vp = (const __half*)vhf + (size_t)s_gidx[e] * 1152 + c;
                v0 = __half2float(vp[0]);    v1 = __half2float(vp[128]);
                v2 = __half2float(vp[256]);  v3 = __half2float(vp[384]);
                v4 = __half2float(vp[512]);  v5 = __half2float(vp[640]);
                v6 = __half2float(vp[768]);  v7 = __half2float(vp[896]);
                v8 = __half2float(vp[1024]);
            } else {
                const float* vp = value + (size_t)s_gidx[e] * 1152 + c;
                v0 = vp[0];    v1 = vp[128];  v2 = vp[256];
                v3 = vp[384];  v4 = vp[512];  v5 = vp[640];
                v6 = vp[768];  v7 = vp[896];  v8 = vp[1024];
            }
            aV[0] = fmaf(av, v0, aV[0]); aV[1] = fmaf(av, v1, aV[1]);
            aV[2] = fmaf(av, v2, aV[2]); aV[3] = fmaf(av, v3, aV[3]);
            aV[4] = fmaf(av, v4, aV[4]); aV[5] = fmaf(av, v5, aV[5]);
            aV[6] = fmaf(av, v6, aV[6]); aV[7] = fmaf(av, v7, aV[7]);
            aV[8] = fmaf(av, v8, aV[8]);
            const float r0 = s_rE[e][0], r1 = s_rE[e][1], r2 = s_rE[e][2];
            const float w0 = av * v0;
            arr[0] = fmaf(r0, w0, arr[0]);
            arr[1] = fmaf(r1, w0, arr[1]);
            arr[2] = fmaf(r2, w0, arr[2]);
            ard = fmaf(av, fmaf(r0, v1, fmaf(r1, v2, r2 * v3)), ard);
        }
        __syncthreads();   // this parity's a-rows fully consumed (all waves)
        const int rb = 16 * ep;   // even -> tiles T0/T2/T4, odd -> T1/T3/T5
        s_buf[swz(rb + 0  + ng, c)] = f2bf(aV[0]);
        s_buf[swz(rb + 4  + ng, c)] = f2bf(aV[1]);
        s_buf[swz(rb + 8  + ng, c)] = f2bf(aV[2]);
        s_buf[swz(rb + 12 + ng, c)] = f2bf(aV[3]);
        s_buf[swz(rb + 32 + ng, c)] = f2bf(ard);
        s_buf[swz(rb + 36 + ng, c)] = f2bf(arr[0]);
        s_buf[swz(rb + 40 + ng, c)] = f2bf(arr[1]);
        s_buf[swz(rb + 44 + ng, c)] = f2bf(arr[2]);
        s_buf[swz(rb + 64 + ng, c)] = f2bf(aV[4]);
        s_buf[swz(rb + 68 + ng, c)] = f2bf(aV[5]);
        s_buf[swz(rb + 72 + ng, c)] = f2bf(aV[6]);
        s_buf[swz(rb + 76 + ng, c)] = f2bf(aV[7]);
        s_buf[swz(96 + 4 * ep + ng, c)] = f2bf(aV[8]);
    }
    __syncthreads();

    // ---------- phase 5: MFMA projection (7 accumulators, 44 MFMAs) -------
    {
        fv4 aEA, aEB, aEC, aOA, aOB, aOC, aG;
        { fv4 z = {0.f,0.f,0.f,0.f}; aEA=z; aEB=z; aEC=z; aOA=z; aOB=z; aOC=z; aG=z; }
        #pragma unroll
        for (int ks = 0; ks < 4; ++ks) {
            const int cb = lq + 4 * ks;
        #define LDA(tb) (*(const bh8*)&s_buf[((tb) + ln15) * 128 + (((cb) ^ (((tb) + ln15) & 7)) << 3)])
        #define LDB(m)  (*(const bh8*)&wcT[(m) * 16384 + (16 * w + ln15) * 128 + lq * 8 + 32 * ks])
            const bh8 W0 = LDB(0), Wd = LDB(1), W1 = LDB(2), Wr = LDB(3), W2 = LDB(4);
            const bh8 A0 = LDA(0),  A2 = LDA(32);
            aEA = MFMA(A0, W0, aEA);  aEA = MFMA(A2, Wd, aEA);
            aEB = MFMA(A0, W1, aEB);  aEB = MFMA(A2, Wr, aEB);
            const bh8 A1 = LDA(16), A3 = LDA(48);
            aOA = MFMA(A1, W0, aOA);  aOA = MFMA(A3, Wd, aOA);
            aOB = MFMA(A1, W1, aOB);  aOB = MFMA(A3, Wr, aOB);
            aEC = MFMA(LDA(64), W2, aEC);
            aOC = MFMA(LDA(80), W2, aOC);
            aG  = MFMA(LDA(96), W2, aG);
        #undef LDA
        #undef LDB
        }
        const int d = 16 * w + ln15;
        const float pb = proj_b[d];
        float* ob = out + (size_t)n0 * 1152 + d;
        #pragma unroll
        for (int r = 0; r < 4; ++r) {
            const int rt = lq * 4 + r;
            const int s = rt & 3;
            {
                const int l4 = 4 + (rt >> 2);
                ob[(size_t)(2 * s) * 1152 + l4 * 128]     = aEC[r];
                ob[(size_t)(2 * s + 1) * 1152 + l4 * 128] = aOC[r];
            }
            if (rt < 4) {
                ob[(size_t)(2 * rt) * 1152]             = aEA[r] + pb;
                ob[(size_t)(2 * rt + 1) * 1152]         = aOA[r] + pb;
                ob[(size_t)(2 * rt) * 1152 + 8 * 128]   = aG[r];
            } else {
                const int l = rt >> 2;
                ob[(size_t)(2 * s) * 1152 + l * 128]     = aEB[r];
                ob[(size_t)(2 * s + 1) * 1152 + l * 128] = aOB[r];
                if (rt < 8)
                    ob[(size_t)(2 * (rt - 4) + 1) * 1152 + 8 * 128] = aG[r];
            }
        }
    }
}

extern "C" void kernel_launch(void* const* d_in, const int* in_sizes, int n_in,
                              void* d_out, int out_size, void* d_ws, size_t ws_size,
                              hipStream_t stream)
{
    const float* alpha        = (const float*)d_in[0];
    const float* value        = (const float*)d_in[1];
    const float* x_edge       = (const float*)d_in[2];
    const float* node_pos     = (const float*)d_in[3];
    const float* edge_dis     = (const float*)d_in[4];
    const float* exp_node_pos = (const float*)d_in[5];
    const float* rad_w1       = (const float*)d_in[6];
    const float* rad_b1       = (const float*)d_in[7];
    const float* ln_g         = (const float*)d_in[8];
    const float* ln_b         = (const float*)d_in[9];
    const float* rad_w2       = (const float*)d_in[10];
    const float* rad_b2       = (const float*)d_in[11];
    const float* tp_w_same    = (const float*)d_in[12];
    const float* tp_w_rv0     = (const float*)d_in[13];
    const float* tp_w_rdot    = (const float*)d_in[14];
    const float* proj_w       = (const float*)d_in[15];
    const float* proj_b       = (const float*)d_in[16];
    const int* outcell_index  = (const int*)d_in[17];
    const int* f_sparse_idx   = (const int*)d_in[18];
    float* out = (float*)d_out;
    unsigned short* ws = (unsigned short*)d_ws;

    const int N = in_sizes[0] / (16 * 8);   // 16000
    const int vElems = in_sizes[1];         // N*1152

    prep_kernel<<<656, 128, 0, stream>>>(rad_w1, rad_w2, tp_w_same, tp_w_rv0,
                                         tp_w_rdot, proj_w, ws);

    const size_t need = ((size_t)106496 + (size_t)vElems) * 2;
    if (ws_size >= need) {
        unsigned short* vhf = ws + 106496;
        const int n8 = vElems / 8;
        conv_value_kernel<<<(n8 + 255) / 256, 256, 0, stream>>>(value, vhf, n8);
        foa_main<1><<<N / NB, BLK, 0, stream>>>(alpha, value, x_edge, node_pos, edge_dis,
                                                exp_node_pos, rad_b1, ln_g, ln_b, rad_b2,
                                                proj_b, ws, vhf, outcell_index,
                                                f_sparse_idx, out);
    } else {
        foa_main<0><<<N / NB, BLK, 0, stream>>>(alpha, value, x_edge, node_pos, edge_dis,
                                                exp_node_pos, rad_b1, ln_g, ln_b, rad_b2,
                                                proj_b, ws, ws, outcell_index,
                                                f_sparse_idx, out);
    }
}

// Round 14
// 152.088 us; speedup vs baseline: 2.1589x; 1.2035x over previous
//
#include <hip/hip_runtime.h>
#include <hip/hip_fp16.h>

typedef __attribute__((ext_vector_type(8))) short bh8;
typedef __attribute__((ext_vector_type(4))) float fv4;

#define NB 8
#define EB 128
#define BLK 512

#define MFMA(a, b, c) __builtin_amdgcn_mfma_f32_16x16x32_bf16((a), (b), (c), 0, 0, 0)

__device__ __forceinline__ unsigned short f2bf(float x) {
    unsigned int u = __float_as_uint(x);
    u += 0x7fffu + ((u >> 16) & 1u);
    return (unsigned short)(u >> 16);
}
__device__ __forceinline__ float bf2f(unsigned short h) {
    return __uint_as_float(((unsigned int)h) << 16);
}
// element index into a row-major [*][128] bf16 LDS tile, 8-elem XOR swizzle
__device__ __forceinline__ int swz(int row, int col) {
    return row * 128 + ((((col >> 3) ^ (row & 7)) << 3) | (col & 7));
}

// ws layout (ushort): [0,8192) w1T[128][64]; [8192,24576) w2T[128][128];
// [24576,106496) wcF[5][8][4][64][8] fragment-packed combined weights;
// [106496, +N*1152) vhf (fp16 value)
__global__ void prep_kernel(
    const float* __restrict__ rad_w1, const float* __restrict__ rad_w2,
    const float* __restrict__ tp_w_same, const float* __restrict__ tp_w_rv0,
    const float* __restrict__ tp_w_rdot, const float* __restrict__ proj_w,
    unsigned short* __restrict__ ws)
{
    unsigned short* w1T = ws;
    unsigned short* w2T = ws + 8192;
    unsigned short* wcF = ws + 24576;
    const int b = blockIdx.x, t = threadIdx.x;
    if (b < 640) {
        const int m = b >> 7, d = b & 127;    // d = output dim (fragment row)
        const float* A; const float* B;
        if (m == 0)      { A = tp_w_same;         B = proj_w; }
        else if (m == 1) { A = tp_w_rdot;         B = proj_w; }
        else if (m == 2) { A = tp_w_same + 16384; B = proj_w + 16384; }
        else if (m == 3) { A = tp_w_rv0;          B = proj_w + 16384; }
        else             { A = tp_w_same + 32768; B = proj_w + 32768; }
        __shared__ float Bs[128];
        Bs[t] = B[t * 128 + d];
        __syncthreads();
        float acc = 0.f;
        const float* Ar = A + t * 128;        // t = input channel c
        #pragma unroll 4
        for (int x = 0; x < 128; ++x) acc = fmaf(Ar[x], Bs[x], acc);
        // fragment-packed store: (m, d, c) -> wcF[((m*8+wt)*4+ks)*512 + lane*8 + j]
        const int wt = d >> 4, l15 = d & 15;
        const int ks = t >> 5, lq = (t & 31) >> 3, j = t & 7;
        const int lane = l15 + 16 * lq;
        wcF[(((m * 8 + wt) * 4 + ks) << 9) + lane * 8 + j] = f2bf(acc);
    } else {
        const int bb = b - 640;
        #pragma unroll
        for (int i = 0; i < 12; ++i) {
            const int idx = bb * 1536 + i * 128 + t;
            if (idx < 8192) {
                const int j = idx >> 6, c = idx & 63;
                w1T[idx] = f2bf(rad_w1[c * 128 + j]);
            } else if (idx < 24576) {
                const int i2 = idx - 8192;
                const int j = i2 >> 7, c = i2 & 127;
                w2T[i2] = f2bf(rad_w2[c * 128 + j]);
            }
        }
    }
}

__global__ __launch_bounds__(256) void conv_value_kernel(
    const float* __restrict__ v, unsigned short* __restrict__ o, int n8)
{
    const int i = blockIdx.x * 256 + threadIdx.x;
    if (i >= n8) return;
    const float4 a = *(const float4*)(v + (size_t)i * 8);
    const float4 b = *(const float4*)(v + (size_t)i * 8 + 4);
    uint4 r;
    r.x = (unsigned int)__half_as_ushort(__float2half_rn(a.x)) |
          ((unsigned int)__half_as_ushort(__float2half_rn(a.y)) << 16);
    r.y = (unsigned int)__half_as_ushort(__float2half_rn(a.z)) |
          ((unsigned int)__half_as_ushort(__float2half_rn(a.w)) << 16);
    r.z = (unsigned int)__half_as_ushort(__float2half_rn(b.x)) |
          ((unsigned int)__half_as_ushort(__float2half_rn(b.y)) << 16);
    r.w = (unsigned int)__half_as_ushort(__float2half_rn(b.z)) |
          ((unsigned int)__half_as_ushort(__float2half_rn(b.w)) << 16);
    *(uint4*)(o + (size_t)i * 8) = r;
}

template <int VHALF>
__global__ __launch_bounds__(BLK, 4) void foa_main(
    const float* __restrict__ alpha,        // [N*K*8]
    const float* __restrict__ value,        // [N][9][128] fp32 (fallback)
    const float* __restrict__ x_edge,       // [N*K][64]
    const float* __restrict__ node_pos,     // [N][3]
    const float* __restrict__ edge_dis,     // [N*K]
    const float* __restrict__ exp_node_pos, // [M][3]
    const float* __restrict__ rad_b1, const float* __restrict__ ln_g,
    const float* __restrict__ ln_b, const float* __restrict__ rad_b2,
    const float* __restrict__ proj_b,
    const unsigned short* __restrict__ ws,
    const unsigned short* __restrict__ vhf, // fp16 value table
    const int* __restrict__ outcell_index,
    const int* __restrict__ f_sparse_idx,
    float* __restrict__ out)                // [N][9][128]
{
    // s_buf: hbuf (ph2) -> a in-place (ph3) -> tpin (parity-split ph4-5)
    // s_w2: stages w1T (16 KB) for ph2, then w2T (32 KB) for ph3
    __shared__ __align__(16) unsigned short s_buf[16384];   // 128 rows x 128
    __shared__ __align__(16) unsigned short s_w2[16384];    // time-shared
    __shared__ float s_alpha[1024];
    __shared__ float s_rE[EB][3];
    __shared__ float s_invd[EB];
    __shared__ int   s_gidx[EB];

    const unsigned short* w1T = ws;
    const unsigned short* w2T = ws + 8192;
    const unsigned short* wcF = ws + 24576;

    const int t = threadIdx.x;
    const int e0 = blockIdx.x * EB;
    const int n0 = blockIdx.x * NB;
    const int lane = t & 63, w = t >> 6;
    const int ln15 = lane & 15, lq = lane >> 4;

    // ---------- phase 0: per-edge metadata + stage w1T into LDS ----------
    if (t < EB) {
        const int eidx = f_sparse_idx[e0 + t];
        s_gidx[t] = outcell_index[eidx];
        const int nn = n0 + (t >> 4);
        s_rE[t][0] = node_pos[nn * 3 + 0] - exp_node_pos[(size_t)eidx * 3 + 0];
        s_rE[t][1] = node_pos[nn * 3 + 1] - exp_node_pos[(size_t)eidx * 3 + 1];
        s_rE[t][2] = node_pos[nn * 3 + 2] - exp_node_pos[(size_t)eidx * 3 + 2];
        s_invd[t] = 1.0f / (edge_dis[e0 + t] + 1e-8f);
    }
    s_alpha[t]       = alpha[(size_t)e0 * 8 + t];
    s_alpha[t + 512] = alpha[(size_t)e0 * 8 + 512 + t];
    // stage w1T [128][64] -> s_w2[0:8192], 8-col-group XOR swizzle
    #pragma unroll
    for (int i = 0; i < 2; ++i) {
        const int chunk = i * BLK + t;            // 1024 chunks x 8 ushorts
        const int row = chunk >> 3, grp = chunk & 7;
        const bh8 v = *(const bh8*)&w1T[row * 64 + grp * 8];
        *(bh8*)&s_w2[row * 64 + ((grp ^ (row & 7)) << 3)] = v;
    }
    __syncthreads();

    // ---------- phase 2: GEMM1 [128,64]@w1(LDS) -> LN -> SiLU -> s_buf ----
    // wave w touches ONLY rows [16w,16w+16) of s_buf in phases 2-3
    {
        bh8 af0, af1;
        {
            const float* xp = x_edge + ((size_t)(e0 + 16 * w + ln15)) * 64 + lq * 8;
            const float4 u0 = *(const float4*)(xp);
            const float4 u1 = *(const float4*)(xp + 4);
            const float4 u2 = *(const float4*)(xp + 32);
            const float4 u3 = *(const float4*)(xp + 36);
            af0[0] = (short)f2bf(u0.x); af0[1] = (short)f2bf(u0.y);
            af0[2] = (short)f2bf(u0.z); af0[3] = (short)f2bf(u0.w);
            af0[4] = (short)f2bf(u1.x); af0[5] = (short)f2bf(u1.y);
            af0[6] = (short)f2bf(u1.z); af0[7] = (short)f2bf(u1.w);
            af1[0] = (short)f2bf(u2.x); af1[1] = (short)f2bf(u2.y);
            af1[2] = (short)f2bf(u2.z); af1[3] = (short)f2bf(u2.w);
            af1[4] = (short)f2bf(u3.x); af1[5] = (short)f2bf(u3.y);
            af1[6] = (short)f2bf(u3.z); af1[7] = (short)f2bf(u3.w);
        }
        fv4 acc1[8];
        #pragma unroll
        for (int ct = 0; ct < 8; ++ct) { fv4 z = {0.f, 0.f, 0.f, 0.f}; acc1[ct] = z; }
        #pragma unroll
        for (int ct = 0; ct < 8; ++ct) {
            const int brow = 16 * ct + ln15;
            const bh8 b0 = *(const bh8*)&s_w2[brow * 64 + ((lq ^ (brow & 7)) << 3)];
            const bh8 b1 = *(const bh8*)&s_w2[brow * 64 + (((lq + 4) ^ (brow & 7)) << 3)];
            acc1[ct] = MFMA(af0, b0, acc1[ct]);
            acc1[ct] = MFMA(af1, b1, acc1[ct]);
        }
        float b1v[8], gv[8], bvv[8];
        #pragma unroll
        for (int ct = 0; ct < 8; ++ct) {
            b1v[ct] = rad_b1[16 * ct + ln15];
            gv[ct]  = ln_g[16 * ct + ln15];
            bvv[ct] = ln_b[16 * ct + ln15];
        }
        #pragma unroll
        for (int r = 0; r < 4; ++r) {
            float vv[8], s = 0.f, s2 = 0.f;
            #pragma unroll
            for (int ct = 0; ct < 8; ++ct) {
                const float x = acc1[ct][r] + b1v[ct];
                vv[ct] = x; s += x; s2 += x * x;
            }
            s += __shfl_xor(s, 1);  s2 += __shfl_xor(s2, 1);
            s += __shfl_xor(s, 2);  s2 += __shfl_xor(s2, 2);
            s += __shfl_xor(s, 4);  s2 += __shfl_xor(s2, 4);
            s += __shfl_xor(s, 8);  s2 += __shfl_xor(s2, 8);
            const float mu = s * 0.0078125f;
            const float var = s2 * 0.0078125f - mu * mu;
            const float rstd = rsqrtf(var + 1e-5f);
            const int rowg = 16 * w + lq * 4 + r;
            #pragma unroll
            for (int ct = 0; ct < 8; ++ct) {
                float hh = (vv[ct] - mu) * rstd * gv[ct] + bvv[ct];
                hh = hh / (1.f + __expf(-hh));
                s_buf[swz(rowg, 16 * ct + ln15)] = f2bf(hh);
            }
        }
    }
    __syncthreads();   // all w1 reads done before overwrite

    // ---------- stage w2T [128][128] -> s_w2, swizzled ----------
    #pragma unroll
    for (int i = 0; i < 4; ++i) {
        const int chunk = i * BLK + t;        // 2048 chunks x 8 ushorts
        const int row = chunk >> 4, grp = chunk & 15;
        const bh8 v = *(const bh8*)&w2T[row * 128 + grp * 8];
        *(bh8*)&s_w2[row * 128 + ((grp ^ (row & 7)) << 3)] = v;
    }
    __syncthreads();

    // ---------- phase 3: GEMM2 in-place, B-frags from LDS -> a (bf16) -----
    {
        bh8 afr[4];
        const int arow = 16 * w + ln15;
        #pragma unroll
        for (int ks = 0; ks < 4; ++ks) {
            const int acb = (lq + 4 * ks) ^ (arow & 7);
            afr[ks] = *(const bh8*)&s_buf[arow * 128 + (acb << 3)];
        }
        fv4 acc2[8];
        #pragma unroll
        for (int ct = 0; ct < 8; ++ct) { fv4 z = {0.f, 0.f, 0.f, 0.f}; acc2[ct] = z; }
        #pragma unroll
        for (int ks = 0; ks < 4; ++ks) {
            #pragma unroll
            for (int ct = 0; ct < 8; ++ct) {
                const int brow = 16 * ct + ln15;
                const bh8 b = *(const bh8*)&s_w2[brow * 128 +
                                  (((lq + 4 * ks) ^ (brow & 7)) << 3)];
                acc2[ct] = MFMA(afr[ks], b, acc2[ct]);
            }
        }
        #pragma unroll
        for (int ct = 0; ct < 8; ++ct) {
            const float b2 = rad_b2[16 * ct + ln15];
            #pragma unroll
            for (int r = 0; r < 4; ++r) {
                const int e = 16 * w + lq * 4 + r;
                const float aval = s_alpha[e * 8 + ct] * (acc2[ct][r] + b2) * s_invd[e];
                s_buf[swz(e, 16 * ct + ln15)] = f2bf(aval);
            }
        }
    }
    __syncthreads();

    // ---------- phase 4: parity-split gather (13 accumulators max) --------
    const int c = t & 127;
    const int ng = t >> 7;
    float aV[9], arr[3], ard;

    #pragma unroll
    for (int ep = 0; ep < 2; ++ep) {
        #pragma unroll
        for (int l = 0; l < 9; ++l) aV[l] = 0.f;
        arr[0] = 0.f; arr[1] = 0.f; arr[2] = 0.f; ard = 0.f;
        #pragma unroll 4
        for (int k = 0; k < 16; ++k) {
            const int e = 32 * ng + 16 * ep + k;
            const float av = bf2f(s_buf[swz(e, c)]);
            float v0, v1, v2, v3, v4, v5, v6, v7, v8;
            if constexpr (VHALF) {
                const __half* vp = (const __half*)vhf + (size_t)s_gidx[e] * 1152 + c;
                v0 = __half2float(vp[0]);    v1 = __half2float(vp[128]);
                v2 = __half2float(vp[256]);  v3 = __half2float(vp[384]);
                v4 = __half2float(vp[512]);  v5 = __half2float(vp[640]);
                v6 = __half2float(vp[768]);  v7 = __half2float(vp[896]);
                v8 = __half2float(vp[1024]);
            } else {
                const float* vp = value + (size_t)s_gidx[e] * 1152 + c;
                v0 = vp[0];    v1 = vp[128];  v2 = vp[256];
                v3 = vp[384];  v4 = vp[512];  v5 = vp[640];
                v6 = vp[768];  v7 = vp[896];  v8 = vp[1024];
            }
            aV[0] = fmaf(av, v0, aV[0]); aV[1] = fmaf(av, v1, aV[1]);
            aV[2] = fmaf(av, v2, aV[2]); aV[3] = fmaf(av, v3, aV[3]);
            aV[4] = fmaf(av, v4, aV[4]); aV[5] = fmaf(av, v5, aV[5]);
            aV[6] = fmaf(av, v6, aV[6]); aV[7] = fmaf(av, v7, aV[7]);
            aV[8] = fmaf(av, v8, aV[8]);
            const float r0 = s_rE[e][0], r1 = s_rE[e][1], r2 = s_rE[e][2];
            const float w0 = av * v0;
            arr[0] = fmaf(r0, w0, arr[0]);
            arr[1] = fmaf(r1, w0, arr[1]);
            arr[2] = fmaf(r2, w0, arr[2]);
            ard = fmaf(av, fmaf(r0, v1, fmaf(r1, v2, r2 * v3)), ard);
        }
        __syncthreads();   // this parity's a-rows fully consumed (all waves)
        const int rb = 16 * ep;   // even -> tiles T0/T2/T4, odd -> T1/T3/T5
        s_buf[swz(rb + 0  + ng, c)] = f2bf(aV[0]);
        s_buf[swz(rb + 4  + ng, c)] = f2bf(aV[1]);
        s_buf[swz(rb + 8  + ng, c)] = f2bf(aV[2]);
        s_buf[swz(rb + 12 + ng, c)] = f2bf(aV[3]);
        s_buf[swz(rb + 32 + ng, c)] = f2bf(ard);
        s_buf[swz(rb + 36 + ng, c)] = f2bf(arr[0]);
        s_buf[swz(rb + 40 + ng, c)] = f2bf(arr[1]);
        s_buf[swz(rb + 44 + ng, c)] = f2bf(arr[2]);
        s_buf[swz(rb + 64 + ng, c)] = f2bf(aV[4]);
        s_buf[swz(rb + 68 + ng, c)] = f2bf(aV[5]);
        s_buf[swz(rb + 72 + ng, c)] = f2bf(aV[6]);
        s_buf[swz(rb + 76 + ng, c)] = f2bf(aV[7]);
        s_buf[swz(96 + 4 * ep + ng, c)] = f2bf(aV[8]);
    }
    __syncthreads();

    // ---------- phase 5: MFMA projection, fragment-packed weights ---------
    {
        fv4 aEA, aEB, aEC, aOA, aOB, aOC, aG;
        { fv4 z = {0.f,0.f,0.f,0.f}; aEA=z; aEB=z; aEC=z; aOA=z; aOB=z; aOC=z; aG=z; }
        #pragma unroll
        for (int ks = 0; ks < 4; ++ks) {
            const int cb = lq + 4 * ks;
        #define LDA(tb) (*(const bh8*)&s_buf[((tb) + ln15) * 128 + (((cb) ^ (((tb) + ln15) & 7)) << 3)])
        #define LDB(m)  (*(const bh8*)&wcF[((((m) * 8 + w) * 4 + ks) << 9) + lane * 8])
            const bh8 W0 = LDB(0), Wd = LDB(1), W1 = LDB(2), Wr = LDB(3), W2 = LDB(4);
            const bh8 A0 = LDA(0),  A2 = LDA(32);
            aEA = MFMA(A0, W0, aEA);  aEA = MFMA(A2, Wd, aEA);
            aEB = MFMA(A0, W1, aEB);  aEB = MFMA(A2, Wr, aEB);
            const bh8 A1 = LDA(16), A3 = LDA(48);
            aOA = MFMA(A1, W0, aOA);  aOA = MFMA(A3, Wd, aOA);
            aOB = MFMA(A1, W1, aOB);  aOB = MFMA(A3, Wr, aOB);
            aEC = MFMA(LDA(64), W2, aEC);
            aOC = MFMA(LDA(80), W2, aOC);
            aG  = MFMA(LDA(96), W2, aG);
        #undef LDA
        #undef LDB
        }
        const int d = 16 * w + ln15;
        const float pb = proj_b[d];
        float* ob = out + (size_t)n0 * 1152 + d;
        #pragma unroll
        for (int r = 0; r < 4; ++r) {
            const int rt = lq * 4 + r;
            const int s = rt & 3;
            {
                const int l4 = 4 + (rt >> 2);
                ob[(size_t)(2 * s) * 1152 + l4 * 128]     = aEC[r];
                ob[(size_t)(2 * s + 1) * 1152 + l4 * 128] = aOC[r];
            }
            if (rt < 4) {
                ob[(size_t)(2 * rt) * 1152]             = aEA[r] + pb;
                ob[(size_t)(2 * rt + 1) * 1152]         = aOA[r] + pb;
                ob[(size_t)(2 * rt) * 1152 + 8 * 128]   = aG[r];
            } else {
                const int l = rt >> 2;
                ob[(size_t)(2 * s) * 1152 + l * 128]     = aEB[r];
                ob[(size_t)(2 * s + 1) * 1152 + l * 128] = aOB[r];
                if (rt < 8)
                    ob[(size_t)(2 * (rt - 4) + 1) * 1152 + 8 * 128] = aG[r];
            }
        }
    }
}

extern "C" void kernel_launch(void* const* d_in, const int* in_sizes, int n_in,
                              void* d_out, int out_size, void* d_ws, size_t ws_size,
                              hipStream_t stream)
{
    const float* alpha        = (const float*)d_in[0];
    const float* value        = (const float*)d_in[1];
    const float* x_edge       = (const float*)d_in[2];
    const float* node_pos     = (const float*)d_in[3];
    const float* edge_dis     = (const float*)d_in[4];
    const float* exp_node_pos = (const float*)d_in[5];
    const float* rad_w1       = (const float*)d_in[6];
    const float* rad_b1       = (const float*)d_in[7];
    const float* ln_g         = (const float*)d_in[8];
    const float* ln_b         = (const float*)d_in[9];
    const float* rad_w2       = (const float*)d_in[10];
    const float* rad_b2       = (const float*)d_in[11];
    const float* tp_w_same    = (const float*)d_in[12];
    const float* tp_w_rv0     = (const float*)d_in[13];
    const float* tp_w_rdot    = (const float*)d_in[14];
    const float* proj_w       = (const float*)d_in[15];
    const float* proj_b       = (const float*)d_in[16];
    const int* outcell_index  = (const int*)d_in[17];
    const int* f_sparse_idx   = (const int*)d_in[18];
    float* out = (float*)d_out;
    unsigned short* ws = (unsigned short*)d_ws;

    const int N = in_sizes[0] / (16 * 8);   // 16000
    const int vElems = in_sizes[1];         // N*1152

    prep_kernel<<<656, 128, 0, stream>>>(rad_w1, rad_w2, tp_w_same, tp_w_rv0,
                                         tp_w_rdot, proj_w, ws);

    const size_t need = ((size_t)106496 + (size_t)vElems) * 2;
    if (ws_size >= need) {
        unsigned short* vhf = ws + 106496;
        const int n8 = vElems / 8;
        conv_value_kernel<<<(n8 + 255) / 256, 256, 0, stream>>>(value, vhf, n8);
        foa_main<1><<<N / NB, BLK, 0, stream>>>(alpha, value, x_edge, node_pos, edge_dis,
                                                exp_node_pos, rad_b1, ln_g, ln_b, rad_b2,
                                                proj_b, ws, vhf, outcell_index,
                                                f_sparse_idx, out);
    } else {
        foa_main<0><<<N / NB, BLK, 0, stream>>>(alpha, value, x_edge, node_pos, edge_dis,
                                                exp_node_pos, rad_b1, ln_g, ln_b, rad_b2,
                                                proj_b, ws, ws, outcell_index,
                                                f_sparse_idx, out);
    }
}